// Round 4
// baseline (22108.774 us; speedup 1.0000x reference)
//
#include <hip/hip_runtime.h>

constexpr int SL  = 384;
constexpr int N2  = SL * SL;      // 147456
constexpr int CH  = 64;
constexpr int D1  = 788;
constexpr int D2  = 210;
constexpr float EPSF = 1e-5f;

// conv tiling
constexpr int TX = 32, TY = 8, HALO = 4;
constexpr int TW = TX + 2 * HALO;          // 40
constexpr int TH = TY + 2 * HALO;          // 16
constexpr int ICS = 8;                     // input channels per stage
constexpr int STAGE = ICS * TW * TH;       // 5120 floats
constexpr int NBLK = (SL / TX) * (SL / TY);// 576 conv blocks

__device__ __forceinline__ float lrelu(float v){ return v >= 0.f ? v : 0.01f * v; }

__device__ __forceinline__ float wred(float v){
  #pragma unroll
  for (int o = 32; o; o >>= 1) v += __shfl_down(v, o, 64);
  return v;
}

// ---------------- per-channel stats (sum, sumsq) over n elements ----------------
__global__ void stats_k(const float* __restrict__ x, int n, float* __restrict__ part){
  const int c = blockIdx.y, s = blockIdx.x, S = gridDim.x;
  const int chunk = (n + S - 1) / S;
  const int st = s * chunk;
  const int en = min(n, st + chunk);
  const float* p = x + (size_t)c * n;
  float sm = 0.f, ss = 0.f;
  for (int i = st + threadIdx.x; i < en; i += blockDim.x){
    float v = p[i]; sm += v; ss += v * v;
  }
  sm = wred(sm); ss = wred(ss);
  __shared__ float aux[8];
  const int wid = threadIdx.x >> 6, lane = threadIdx.x & 63;
  if (lane == 0){ aux[wid] = sm; aux[4 + wid] = ss; }
  __syncthreads();
  if (threadIdx.x == 0){
    part[((size_t)c * S + s) * 2]     = aux[0] + aux[1] + aux[2] + aux[3];
    part[((size_t)c * S + s) * 2 + 1] = aux[4] + aux[5] + aux[6] + aux[7];
  }
}

__global__ void stats_final_k(const float* __restrict__ part, int C, int S, float ninv,
                              float* __restrict__ mean, float* __restrict__ rstd){
  const int c = blockIdx.x * blockDim.x + threadIdx.x;
  if (c >= C) return;
  float sm = 0.f, ss = 0.f;
  for (int s = 0; s < S; ++s){ sm += part[((size_t)c * S + s) * 2]; ss += part[((size_t)c * S + s) * 2 + 1]; }
  const float m = sm * ninv;
  const float v = ss * ninv - m * m;
  mean[c] = m;
  rstd[c] = rsqrtf(v + EPSF);
}

// ---------------- 1d branch ----------------
// x1's mean cancels in pair1's inorm (constant per output channel); apply rstd only.
__global__ void rowcol_k(const float* __restrict__ x1d, const float* __restrict__ W1,
                         const float* __restrict__ r1,
                         float* __restrict__ row, float* __restrict__ col){
  const int idx = blockIdx.x * 256 + threadIdx.x;      // 0 .. 2*64*384-1
  const int half = idx / (CH * SL);
  const int rem  = idx % (CH * SL);
  const int c = rem / SL, l = rem % SL;
  const float* wp = W1 + (size_t)c * (2 * D1) + (size_t)half * D1;  // wave-uniform
  float acc = 0.f;
  for (int d = 0; d < D1; ++d)
    acc += wp[d] * (x1d[(size_t)d * SL + l] * r1[d]);
  (half ? col : row)[c * SL + l] = acc;
}

// Var(row_i + col_j) = Var(row)+Var(col); mean = mean(row)+mean(col)  (exact)
__global__ void rowcol_stats_k(const float* __restrict__ row, const float* __restrict__ col,
                               float* __restrict__ m1, float* __restrict__ rs1){
  const int c = blockIdx.x;
  float sr = 0, ssr = 0, sc = 0, ssc = 0;
  for (int i = threadIdx.x; i < SL; i += blockDim.x){
    float r = row[c * SL + i]; sr += r; ssr += r * r;
    float q = col[c * SL + i]; sc += q; ssc += q * q;
  }
  sr = wred(sr); ssr = wred(ssr); sc = wred(sc); ssc = wred(ssc);
  __shared__ float aux[16];
  const int wid = threadIdx.x >> 6, lane = threadIdx.x & 63;
  if (lane == 0){ aux[wid] = sr; aux[4+wid] = ssr; aux[8+wid] = sc; aux[12+wid] = ssc; }
  __syncthreads();
  if (threadIdx.x == 0){
    float a = 0, b = 0, d = 0, e = 0;
    for (int i = 0; i < 4; ++i){ a += aux[i]; b += aux[4+i]; d += aux[8+i]; e += aux[12+i]; }
    const float mr = a / SL, mc = d / SL;
    const float vr = b / SL - mr * mr, vc = e / SL - mc * mc;
    m1[c]  = mr + mc;
    rs1[c] = rsqrtf(vr + vc + EPSF);
  }
}

__global__ void pair1n_k(const float* __restrict__ row, const float* __restrict__ col,
                         const float* __restrict__ m1, const float* __restrict__ rs1,
                         const float* __restrict__ g1, const float* __restrict__ b1,
                         float* __restrict__ out){
  const int c = blockIdx.y;
  const int p = blockIdx.x * 256 + threadIdx.x;
  const float a  = rs1[c] * g1[c];
  const float bb = b1[c] - m1[c] * a;
  const float v = row[c * SL + p / SL] + col[c * SL + p % SL];
  out[(size_t)c * N2 + p] = lrelu(v * a + bb);
}

// ---------------- 2d branch: x2 rstd folds into W2 (x2 mean cancels in pair2 inorm) ----
__global__ void w2eff_k(const float* __restrict__ W2, const float* __restrict__ r2,
                        float* __restrict__ w2e){
  const int c = threadIdx.x;
  if (c >= CH) return;
  for (int d = 0; d < D2; ++d)
    w2e[d * CH + c] = W2[(size_t)c * D2 + d] * r2[d];   // transposed [d][c]
}

__global__ __launch_bounds__(256) void gemm_pair2_k(const float* __restrict__ x2,
                                                    const float* __restrict__ w2e,
                                                    float* __restrict__ out){
  const int p = blockIdx.x * 256 + threadIdx.x;
  float acc[CH];
  #pragma unroll
  for (int c = 0; c < CH; ++c) acc[c] = 0.f;
  for (int d = 0; d < D2; ++d){
    const float xv = x2[(size_t)d * N2 + p];
    const float4* w4 = (const float4*)(w2e + d * CH);   // wave-uniform -> scalar loads
    #pragma unroll
    for (int q = 0; q < CH / 4; ++q){
      float4 w = w4[q];
      acc[4*q] += w.x*xv; acc[4*q+1] += w.y*xv; acc[4*q+2] += w.z*xv; acc[4*q+3] += w.w*xv;
    }
  }
  #pragma unroll
  for (int c = 0; c < CH; ++c)
    out[(size_t)c * N2 + p] = acc[c];
}

__global__ void w3t_k(const float* __restrict__ W3, float* __restrict__ w3t){
  const int i = blockIdx.x * 256 + threadIdx.x;
  if (i >= CH * 2 * CH) return;
  const int c = i / (2 * CH), e = i % (2 * CH);
  w3t[e * CH + c] = W3[i];
}

__global__ __launch_bounds__(256) void gemm_mix_k(const float* __restrict__ A,
                                                  const float* __restrict__ B,
                                                  const float* __restrict__ w3t,
                                                  float* __restrict__ out){
  const int p = blockIdx.x * 256 + threadIdx.x;
  float acc[CH];
  #pragma unroll
  for (int c = 0; c < CH; ++c) acc[c] = 0.f;
  for (int e = 0; e < CH; ++e){
    const float xv = A[(size_t)e * N2 + p];
    const float4* w4 = (const float4*)(w3t + e * CH);
    #pragma unroll
    for (int q = 0; q < CH / 4; ++q){
      float4 w = w4[q];
      acc[4*q] += w.x*xv; acc[4*q+1] += w.y*xv; acc[4*q+2] += w.z*xv; acc[4*q+3] += w.w*xv;
    }
  }
  for (int e = 0; e < CH; ++e){
    const float xv = B[(size_t)e * N2 + p];
    const float4* w4 = (const float4*)(w3t + (CH + e) * CH);
    #pragma unroll
    for (int q = 0; q < CH / 4; ++q){
      float4 w = w4[q];
      acc[4*q] += w.x*xv; acc[4*q+1] += w.y*xv; acc[4*q+2] += w.z*xv; acc[4*q+3] += w.w*xv;
    }
  }
  #pragma unroll
  for (int c = 0; c < CH; ++c)
    out[(size_t)c * N2 + p] = acc[c];
}

// ---------------- inorm-affine + leaky (+ optional residual add) ----------------
__global__ void normleaky_k(const float* __restrict__ src, float* __restrict__ dst,
                            const float* __restrict__ mean, const float* __restrict__ rstd,
                            const float* __restrict__ g, const float* __restrict__ be,
                            int goff, const float* __restrict__ res){
  const int c = blockIdx.y;
  const int p = blockIdx.x * 256 + threadIdx.x;
  const size_t idx = (size_t)c * N2 + p;
  const float a  = rstd[c] * g[goff + c];
  const float bb = be[goff + c] - mean[c] * a;
  float v = lrelu(src[idx] * a + bb);
  if (res) v += res[idx];
  dst[idx] = v;
}

// conv weights [conv][oc][ic][3][3] -> [conv][ic][tap][oc]  (conv bias cancels in inorm)
__global__ void wt_k(const float* __restrict__ w, float* __restrict__ wt){
  const int i = blockIdx.x * 256 + threadIdx.x;
  if (i >= 10 * CH * CH * 9) return;
  const int oc  = i % CH;
  const int tap = (i / CH) % 9;
  const int ic  = (i / (CH * 9)) % CH;
  const int cv  = i / (CH * 9 * CH);
  wt[i] = w[((size_t)(cv * CH + oc) * CH + ic) * 9 + tap];
}

// ---------------- dilated 3x3 conv: block = 32x8 pixel tile, thread = 1 px * 64 oc ----
// Double-buffered LDS input staging (8 ic/stage); fused per-channel stats epilogue.
template<int DIL>
__global__ __launch_bounds__(256) void conv_k(const float* __restrict__ in,
                                              const float* __restrict__ wt,
                                              float* __restrict__ out,
                                              float* __restrict__ part){
  __shared__ float lds[2][STAGE];
  const int tid = threadIdx.x;
  const int bx = blockIdx.x % (SL / TX), by = blockIdx.x / (SL / TX);
  const int x0 = bx * TX - HALO, y0 = by * TY - HALO;
  const int tx = tid % TX, ty = tid / TX;

  float acc[CH];
  #pragma unroll
  for (int o = 0; o < CH; ++o) acc[o] = 0.f;

  float reg[STAGE / 256];                       // 20 staging regs
  // prologue: stage ic 0..7
  #pragma unroll
  for (int r = 0; r < STAGE / 256; ++r){
    const int idx = tid + r * 256;
    const int icL = idx / (TW * TH), rem = idx % (TW * TH);
    const int sy = rem / TW, sx = rem % TW;
    const int gx = x0 + sx, gy = y0 + sy;
    const bool ok = ((unsigned)gx < (unsigned)SL) && ((unsigned)gy < (unsigned)SL);
    reg[r] = ok ? in[(size_t)icL * N2 + gy * SL + gx] : 0.f;
  }
  #pragma unroll
  for (int r = 0; r < STAGE / 256; ++r) lds[0][tid + r * 256] = reg[r];
  __syncthreads();

  for (int s = 0; s < CH / ICS; ++s){
    const int cur = s & 1;
    // issue next stage's global loads (overlap with FMAs below)
    if (s + 1 < CH / ICS){
      const int icB = (s + 1) * ICS;
      #pragma unroll
      for (int r = 0; r < STAGE / 256; ++r){
        const int idx = tid + r * 256;
        const int icL = idx / (TW * TH), rem = idx % (TW * TH);
        const int sy = rem / TW, sx = rem % TW;
        const int gx = x0 + sx, gy = y0 + sy;
        const bool ok = ((unsigned)gx < (unsigned)SL) && ((unsigned)gy < (unsigned)SL);
        reg[r] = ok ? in[(size_t)(icB + icL) * N2 + gy * SL + gx] : 0.f;
      }
    }
    // compute current stage from LDS
    const float* buf = lds[cur];
    #pragma unroll
    for (int icL = 0; icL < ICS; ++icL){
      const int ic = s * ICS + icL;
      const float* wb = wt + (size_t)(ic * 9) * CH;    // wave-uniform -> s_load
      #pragma unroll
      for (int ky = 0; ky < 3; ++ky){
        #pragma unroll
        for (int kx = 0; kx < 3; ++kx){
          const float xv = buf[icL * (TW * TH) + (ty + HALO + (ky - 1) * DIL) * TW
                               + (tx + HALO + (kx - 1) * DIL)];
          const float4* w4 = (const float4*)(wb + (ky * 3 + kx) * CH);
          #pragma unroll
          for (int q = 0; q < CH / 4; ++q){
            float4 w = w4[q];
            acc[4*q]   += w.x*xv; acc[4*q+1] += w.y*xv;
            acc[4*q+2] += w.z*xv; acc[4*q+3] += w.w*xv;
          }
        }
      }
    }
    if (s + 1 < CH / ICS){
      #pragma unroll
      for (int r = 0; r < STAGE / 256; ++r) lds[1 - cur][tid + r * 256] = reg[r];
      __syncthreads();
    }
  }

  // store
  const int p = (by * TY + ty) * SL + bx * TX + tx;
  #pragma unroll
  for (int o = 0; o < CH; ++o)
    out[(size_t)o * N2 + p] = acc[o];

  // fused per-channel stats partials (sum, sumsq over this block's 256 pixels)
  __syncthreads();                              // done reading lds; reuse as scratch
  float* rb = &lds[0][0];                       // [4 waves][64 ch][2]
  const int wid = tid >> 6, lane = tid & 63;
  #pragma unroll
  for (int c = 0; c < CH; ++c){
    const float sm = wred(acc[c]);
    const float ss = wred(acc[c] * acc[c]);
    if (lane == 0){ rb[(wid * CH + c) * 2] = sm; rb[(wid * CH + c) * 2 + 1] = ss; }
  }
  __syncthreads();
  if (tid < CH){
    float sm = 0.f, ss = 0.f;
    #pragma unroll
    for (int w = 0; w < 4; ++w){ sm += rb[(w * CH + tid) * 2]; ss += rb[(w * CH + tid) * 2 + 1]; }
    part[((size_t)tid * NBLK + blockIdx.x) * 2]     = sm;
    part[((size_t)tid * NBLK + blockIdx.x) * 2 + 1] = ss;
  }
}

static void launch_conv(int dil, const float* src, const float* wtl, float* dst,
                        float* part, hipStream_t s){
  switch (dil){
    case 1:  conv_k<1><<<NBLK, 256, 0, s>>>(src, wtl, dst, part); break;
    case 2:  conv_k<2><<<NBLK, 256, 0, s>>>(src, wtl, dst, part); break;
    default: conv_k<4><<<NBLK, 256, 0, s>>>(src, wtl, dst, part); break;
  }
}

extern "C" void kernel_launch(void* const* d_in, const int* in_sizes, int n_in,
                              void* d_out, int out_size, void* d_ws, size_t ws_size,
                              hipStream_t stream){
  const float* x1d    = (const float*)d_in[0];
  const float* x2     = (const float*)d_in[1];
  const float* W1     = (const float*)d_in[2];
  const float* g1     = (const float*)d_in[3];
  const float* b1     = (const float*)d_in[4];
  const float* W2     = (const float*)d_in[5];
  const float* res_w  = (const float*)d_in[11];
  // d_in[12] = res_b: cancels exactly in the following instance-norm
  const float* res_g  = (const float*)d_in[13];
  const float* res_be = (const float*)d_in[14];
  float* X = (float*)d_out;          // residual stream lives in d_out (fp32)

  float* ws = (float*)d_ws;
  float* A    = ws; ws += (size_t)CH * N2;     // 37.75 MB
  float* Bb   = ws; ws += (size_t)CH * N2;     // 37.75 MB
  float* row  = ws; ws += CH * SL;
  float* col  = ws; ws += CH * SL;
  float* s1m  = ws; ws += D1;   float* s1r  = ws; ws += D1;
  float* s2m  = ws; ws += 256;  float* s2r  = ws; ws += 256;
  float* m1   = ws; ws += 64;   float* rs1  = ws; ws += 64;
  float* smv  = ws; ws += 64;   float* srv  = ws; ws += 64;
  float* w2e  = ws; ws += D2 * CH;
  float* w3t  = ws; ws += 2 * CH * CH;
  float* wt   = ws; ws += 10 * CH * CH * 9;
  float* part = ws; ws += CH * NBLK * 2;       // 73728 floats (covers all stats uses)

  // ---- 1d branch
  stats_k<<<dim3(1, D1), 256, 0, stream>>>(x1d, SL, part);
  stats_final_k<<<(D1 + 255) / 256, 256, 0, stream>>>(part, D1, 1, 1.f / SL, s1m, s1r);
  rowcol_k<<<2 * CH * SL / 256, 256, 0, stream>>>(x1d, W1, s1r, row, col);
  rowcol_stats_k<<<CH, 256, 0, stream>>>(row, col, m1, rs1);
  pair1n_k<<<dim3(N2 / 256, CH), 256, 0, stream>>>(row, col, m1, rs1, g1, b1, A);

  // ---- 2d branch
  stats_k<<<dim3(16, D2), 256, 0, stream>>>(x2, N2, part);
  stats_final_k<<<1, 256, 0, stream>>>(part, D2, 16, 1.f / N2, s2m, s2r);
  w2eff_k<<<1, 64, 0, stream>>>(W2, s2r, w2e);
  gemm_pair2_k<<<N2 / 256, 256, 0, stream>>>(x2, w2e, Bb);
  stats_k<<<dim3(16, CH), 256, 0, stream>>>(Bb, N2, part);
  stats_final_k<<<1, 256, 0, stream>>>(part, CH, 16, 1.f / N2, smv, srv);
  normleaky_k<<<dim3(N2 / 256, CH), 256, 0, stream>>>(Bb, Bb, smv, srv,
      (const float*)d_in[6], (const float*)d_in[7], 0, nullptr);

  // ---- mix
  w3t_k<<<(2 * CH * CH + 255) / 256, 256, 0, stream>>>((const float*)d_in[8], w3t);
  gemm_mix_k<<<N2 / 256, 256, 0, stream>>>(A, Bb, w3t, X);
  stats_k<<<dim3(16, CH), 256, 0, stream>>>(X, N2, part);
  stats_final_k<<<1, 256, 0, stream>>>(part, CH, 16, 1.f / N2, smv, srv);
  normleaky_k<<<dim3(N2 / 256, CH), 256, 0, stream>>>(X, X, smv, srv,
      (const float*)d_in[9], (const float*)d_in[10], 0, nullptr);

  // ---- conv weights
  wt_k<<<(10 * CH * CH * 9 + 255) / 256, 256, 0, stream>>>(res_w, wt);

  // ---- 5 residual layers x 2 convs (stats fused into conv epilogue)
  const int dil[5] = {1, 2, 4, 2, 1};
  for (int layer = 0; layer < 5; ++layer){
    for (int k = 0; k < 2; ++k){
      const int li = layer * 2 + k;
      const float* wtl = wt + (size_t)li * CH * CH * 9;
      float* dst = (k == 0) ? A : Bb;
      launch_conv(dil[layer], (k == 0) ? X : A, wtl, dst, part, stream);
      stats_final_k<<<1, 256, 0, stream>>>(part, CH, NBLK, 1.f / N2, smv, srv);
      if (k == 0)
        normleaky_k<<<dim3(N2 / 256, CH), 256, 0, stream>>>(A, A, smv, srv,
            res_g, res_be, li * CH, nullptr);
      else   // x = lrelu(inorm(conv2)) + res
        normleaky_k<<<dim3(N2 / 256, CH), 256, 0, stream>>>(Bb, X, smv, srv,
            res_g, res_be, li * CH, X);
    }
  }
}

// Round 5
// 2081.368 us; speedup vs baseline: 10.6222x; 10.6222x over previous
//
#include <hip/hip_runtime.h>
#include <hip/hip_bf16.h>

typedef __attribute__((ext_vector_type(8)))  short short8;
typedef __attribute__((ext_vector_type(16))) float floatx16;
typedef unsigned short ushort;

constexpr int SL  = 384;
constexpr int N2  = SL * SL;      // 147456
constexpr int CH  = 64;
constexpr int D1  = 788;
constexpr int D2  = 210;
constexpr float EPSF = 1e-5f;

constexpr int TX = 32, TY = 8;
constexpr int NBLK = (SL / TX) * (SL / TY);   // 576

__device__ __forceinline__ float lrelu(float v){ return v >= 0.f ? v : 0.01f * v; }
__device__ __forceinline__ ushort f2b(float f){
  __hip_bfloat16 h = __float2bfloat16(f); return *(ushort*)&h;
}
__device__ __forceinline__ float b2f(ushort u){
  __hip_bfloat16 h = *(__hip_bfloat16*)&u; return __bfloat162float(h);
}
__device__ __forceinline__ float ldv(const float* p, size_t i){ return p[i]; }
__device__ __forceinline__ float ldv(const ushort* p, size_t i){ return b2f(p[i]); }

__device__ __forceinline__ float wred(float v){
  #pragma unroll
  for (int o = 32; o; o >>= 1) v += __shfl_down(v, o, 64);
  return v;
}

// ---------------- per-channel stats (sum, sumsq) ----------------
template<typename T>
__global__ void stats_k(const T* __restrict__ x, int n, float* __restrict__ part){
  const int c = blockIdx.y, s = blockIdx.x, S = gridDim.x;
  const int chunk = (n + S - 1) / S;
  const int st = s * chunk, en = min(n, st + chunk);
  const T* p = x + (size_t)c * n;
  float sm = 0.f, ss = 0.f;
  for (int i = st + threadIdx.x; i < en; i += blockDim.x){
    float v = ldv(p, i); sm += v; ss += v * v;
  }
  sm = wred(sm); ss = wred(ss);
  __shared__ float aux[8];
  const int wid = threadIdx.x >> 6, lane = threadIdx.x & 63;
  if (lane == 0){ aux[wid] = sm; aux[4 + wid] = ss; }
  __syncthreads();
  if (threadIdx.x == 0){
    part[((size_t)c * S + s) * 2]     = aux[0] + aux[1] + aux[2] + aux[3];
    part[((size_t)c * S + s) * 2 + 1] = aux[4] + aux[5] + aux[6] + aux[7];
  }
}

// raw mean/rstd (for x1d, x2 folds)
__global__ void stats_final_k(const float* __restrict__ part, int C, int S, float ninv,
                              float* __restrict__ mean, float* __restrict__ rstd){
  const int c = blockIdx.x * blockDim.x + threadIdx.x;
  if (c >= C) return;
  float sm = 0.f, ss = 0.f;
  for (int s = 0; s < S; ++s){ sm += part[((size_t)c * S + s) * 2]; ss += part[((size_t)c * S + s) * 2 + 1]; }
  const float m = sm * ninv;
  mean[c] = m;
  rstd[c] = rsqrtf(ss * ninv - m * m + EPSF);
}

// finalize into affine a,b: y = x*a[c]+b[c] equals gamma*(x-mu)*rstd+beta
__global__ void statsaffine_k(const float* __restrict__ part, int S, float ninv,
                              const float* __restrict__ g, const float* __restrict__ be,
                              int goff, float* __restrict__ ao, float* __restrict__ bo){
  const int c = threadIdx.x;
  if (c >= CH) return;
  float sm = 0.f, ss = 0.f;
  for (int s = 0; s < S; ++s){ sm += part[((size_t)c * S + s) * 2]; ss += part[((size_t)c * S + s) * 2 + 1]; }
  const float m = sm * ninv;
  const float r = rsqrtf(ss * ninv - m * m + EPSF);
  const float a = r * g[goff + c];
  ao[c] = a;
  bo[c] = be[goff + c] - m * a;
}

// ---------------- 1d branch ----------------
__global__ void rowcol_k(const float* __restrict__ x1d, const float* __restrict__ W1,
                         const float* __restrict__ r1,
                         float* __restrict__ row, float* __restrict__ col){
  const int idx = blockIdx.x * 256 + threadIdx.x;
  const int half = idx / (CH * SL);
  const int rem  = idx % (CH * SL);
  const int c = rem / SL, l = rem % SL;
  const float* wp = W1 + (size_t)c * (2 * D1) + (size_t)half * D1;
  float acc = 0.f;
  for (int d = 0; d < D1; ++d)
    acc += wp[d] * (x1d[(size_t)d * SL + l] * r1[d]);
  (half ? col : row)[c * SL + l] = acc;
}

__global__ void rowcol_stats_k(const float* __restrict__ row, const float* __restrict__ col,
                               float* __restrict__ m1, float* __restrict__ rs1){
  const int c = blockIdx.x;
  float sr = 0, ssr = 0, sc = 0, ssc = 0;
  for (int i = threadIdx.x; i < SL; i += blockDim.x){
    float r = row[c * SL + i]; sr += r; ssr += r * r;
    float q = col[c * SL + i]; sc += q; ssc += q * q;
  }
  sr = wred(sr); ssr = wred(ssr); sc = wred(sc); ssc = wred(ssc);
  __shared__ float aux[16];
  const int wid = threadIdx.x >> 6, lane = threadIdx.x & 63;
  if (lane == 0){ aux[wid] = sr; aux[4+wid] = ssr; aux[8+wid] = sc; aux[12+wid] = ssc; }
  __syncthreads();
  if (threadIdx.x == 0){
    float a = 0, b = 0, d = 0, e = 0;
    for (int i = 0; i < 4; ++i){ a += aux[i]; b += aux[4+i]; d += aux[8+i]; e += aux[12+i]; }
    const float mr = a / SL, mc = d / SL;
    const float vr = b / SL - mr * mr, vc = e / SL - mc * mc;
    m1[c]  = mr + mc;
    rs1[c] = rsqrtf(vr + vc + EPSF);
  }
}

__global__ void pair1n_k(const float* __restrict__ row, const float* __restrict__ col,
                         const float* __restrict__ m1, const float* __restrict__ rs1,
                         const float* __restrict__ g1, const float* __restrict__ b1,
                         ushort* __restrict__ out){
  const int c = blockIdx.y;
  const int p = blockIdx.x * 256 + threadIdx.x;
  const float a  = rs1[c] * g1[c];
  const float bb = b1[c] - m1[c] * a;
  const float v = row[c * SL + p / SL] + col[c * SL + p % SL];
  out[(size_t)c * N2 + p] = f2b(lrelu(v * a + bb));
}

// ---------------- 2d branch ----------------
__global__ void w2eff_k(const float* __restrict__ W2, const float* __restrict__ r2,
                        float* __restrict__ w2e){
  const int c = threadIdx.x;
  if (c >= CH) return;
  for (int d = 0; d < D2; ++d)
    w2e[d * CH + c] = W2[(size_t)c * D2 + d] * r2[d];
}

__global__ __launch_bounds__(256) void gemm_pair2_k(const float* __restrict__ x2,
                                                    const float* __restrict__ w2e,
                                                    ushort* __restrict__ out){
  const int p = blockIdx.x * 256 + threadIdx.x;
  float acc[CH];
  #pragma unroll
  for (int c = 0; c < CH; ++c) acc[c] = 0.f;
  for (int d = 0; d < D2; ++d){
    const float xv = x2[(size_t)d * N2 + p];
    const float4* w4 = (const float4*)(w2e + d * CH);
    #pragma unroll
    for (int q = 0; q < CH / 4; ++q){
      float4 w = w4[q];
      acc[4*q] += w.x*xv; acc[4*q+1] += w.y*xv; acc[4*q+2] += w.z*xv; acc[4*q+3] += w.w*xv;
    }
  }
  #pragma unroll
  for (int c = 0; c < CH; ++c)
    out[(size_t)c * N2 + p] = f2b(acc[c]);
}

__global__ void w3t_k(const float* __restrict__ W3, float* __restrict__ w3t){
  const int i = blockIdx.x * 256 + threadIdx.x;
  if (i >= CH * 2 * CH) return;
  const int c = i / (2 * CH), e = i % (2 * CH);
  w3t[e * CH + c] = W3[i];
}

__global__ __launch_bounds__(256) void gemm_mix_k(const ushort* __restrict__ A,
                                                  const ushort* __restrict__ B,
                                                  const float* __restrict__ w3t,
                                                  float* __restrict__ out){
  const int p = blockIdx.x * 256 + threadIdx.x;
  float acc[CH];
  #pragma unroll
  for (int c = 0; c < CH; ++c) acc[c] = 0.f;
  for (int e = 0; e < CH; ++e){
    const float xv = b2f(A[(size_t)e * N2 + p]);
    const float4* w4 = (const float4*)(w3t + e * CH);
    #pragma unroll
    for (int q = 0; q < CH / 4; ++q){
      float4 w = w4[q];
      acc[4*q] += w.x*xv; acc[4*q+1] += w.y*xv; acc[4*q+2] += w.z*xv; acc[4*q+3] += w.w*xv;
    }
  }
  for (int e = 0; e < CH; ++e){
    const float xv = b2f(B[(size_t)e * N2 + p]);
    const float4* w4 = (const float4*)(w3t + (CH + e) * CH);
    #pragma unroll
    for (int q = 0; q < CH / 4; ++q){
      float4 w = w4[q];
      acc[4*q] += w.x*xv; acc[4*q+1] += w.y*xv; acc[4*q+2] += w.z*xv; acc[4*q+3] += w.w*xv;
    }
  }
  #pragma unroll
  for (int c = 0; c < CH; ++c)
    out[(size_t)c * N2 + p] = acc[c];
}

// ---------------- norm+leaky (affine form), optional residual ----------------
template<typename TS, typename TD>
__global__ void normleaky_k(const TS* __restrict__ src, TD* __restrict__ dst,
                            const float* __restrict__ a, const float* __restrict__ b,
                            const TD* __restrict__ res){
  const int c = blockIdx.y;
  const int p = blockIdx.x * 256 + threadIdx.x;
  const size_t idx = (size_t)c * N2 + p;
  float v = lrelu(ldv(src, idx) * a[c] + b[c]);
  if (res) v += ldv(res, idx);
  if constexpr (sizeof(TD) == 2) dst[idx] = f2b(v); else dst[idx] = v;
}

// conv weights [conv][oc][ic][3][3] fp32 -> bf16 [conv][tap][kc][half][oc][8j]
// (ic = kc*16 + half*8 + j). Conv bias cancels in the following instance-norm.
__global__ void wt_k(const float* __restrict__ w, ushort* __restrict__ wt){
  const int i = blockIdx.x * 256 + threadIdx.x;   // 10*9*4*2*64*8 = 368640
  const int j    = i & 7;
  const int oc   = (i >> 3) & 63;
  const int half = (i >> 9) & 1;
  const int kc   = (i >> 10) & 3;
  const int tap  = (i / 4096) % 9;
  const int cv   = i / 36864;
  const int ic   = kc * 16 + half * 8 + j;
  wt[i] = f2b(w[((size_t)(cv * CH + oc) * CH + ic) * 9 + tap]);
}

// ---------------- MFMA conv: 32x8 px tile, wave = 64oc x 64px ----------------
// LDS: input tile [slot][64 ic] bf16, 16B chunks XOR-swizzled by (slot&7).
// Optional fused pre-norm+leaky (a,b) applied to input during staging.
template<int DIL, typename TIN>
__global__ __launch_bounds__(256) void convm_k(const TIN* __restrict__ in,
                                               const ushort* __restrict__ wg,
                                               const float* __restrict__ na,
                                               const float* __restrict__ nb,
                                               ushort* __restrict__ out,
                                               float* __restrict__ part){
  constexpr int TWd = TX + 2 * DIL, THd = TY + 2 * DIL, NSLOT = TWd * THd;
  __shared__ __align__(16) ushort ilds[NSLOT * 64];
  const int tid = threadIdx.x;
  const int bx = blockIdx.x % (SL / TX), by = blockIdx.x / (SL / TX);
  const int x0 = bx * TX - DIL, y0 = by * TY - DIL;
  const bool donorm = (na != nullptr);

  // ---- stage input tile (bf16, swizzled), zero-pad OOB AFTER norm ----
  for (int chk = 0; chk < 8; ++chk){
    for (int s = tid; s < NSLOT; s += 256){
      const int sy = s / TWd, sx = s % TWd;
      const int gx = x0 + sx, gy = y0 + sy;
      const bool ok = ((unsigned)gx < (unsigned)SL) && ((unsigned)gy < (unsigned)SL);
      short8 v8;
      #pragma unroll
      for (int j = 0; j < 8; ++j){
        const int ic = chk * 8 + j;
        float v = 0.f;
        if (ok){
          v = ldv(in, (size_t)ic * N2 + gy * SL + gx);
          if (donorm) v = lrelu(v * na[ic] + nb[ic]);
        }
        v8[j] = (short)f2b(v);
      }
      *(short8*)&ilds[s * 64 + ((chk ^ (s & 7)) * 8)] = v8;
    }
  }
  __syncthreads();

  // ---- MFMA main loop ----
  const int lane = tid & 63, wid = tid >> 6;
  const int ln = lane & 31, half = lane >> 5;
  floatx16 acc[2][2];
  #pragma unroll
  for (int mt = 0; mt < 2; ++mt)
    #pragma unroll
    for (int nt = 0; nt < 2; ++nt)
      #pragma unroll
      for (int r = 0; r < 16; ++r) acc[mt][nt][r] = 0.f;

  const int r0 = 2 * wid;
  #pragma unroll
  for (int tap = 0; tap < 9; ++tap){
    const int ky = tap / 3, kx = tap % 3;
    const int sx = ln + kx * DIL;
    const int slot0 = (r0 + ky * DIL) * TWd + sx;
    const int slot1 = slot0 + TWd;
    #pragma unroll
    for (int kc = 0; kc < 4; ++kc){
      const int chkB = kc * 2 + half;
      const size_t abase = (size_t)(((tap * 4 + kc) * 2 + half) * 64) * 8;
      short8 a0 = *(const short8*)&wg[abase + (size_t)ln * 8];
      short8 a1 = *(const short8*)&wg[abase + (size_t)(32 + ln) * 8];
      short8 b0 = *(const short8*)&ilds[slot0 * 64 + ((chkB ^ (slot0 & 7)) * 8)];
      short8 b1 = *(const short8*)&ilds[slot1 * 64 + ((chkB ^ (slot1 & 7)) * 8)];
      acc[0][0] = __builtin_amdgcn_mfma_f32_32x32x16_bf16(a0, b0, acc[0][0], 0, 0, 0);
      acc[1][0] = __builtin_amdgcn_mfma_f32_32x32x16_bf16(a1, b0, acc[1][0], 0, 0, 0);
      acc[0][1] = __builtin_amdgcn_mfma_f32_32x32x16_bf16(a0, b1, acc[0][1], 0, 0, 0);
      acc[1][1] = __builtin_amdgcn_mfma_f32_32x32x16_bf16(a1, b1, acc[1][1], 0, 0, 0);
    }
  }

  // ---- store raw conv out (bf16) ----
  const int px0 = bx * TX + ln;
  #pragma unroll
  for (int mt = 0; mt < 2; ++mt)
    #pragma unroll
    for (int nt = 0; nt < 2; ++nt){
      const int rowg = by * TY + r0 + nt;
      #pragma unroll
      for (int r = 0; r < 16; ++r){
        const int oc = mt * 32 + (r & 3) + 8 * (r >> 2) + 4 * half;
        out[(size_t)oc * N2 + rowg * SL + px0] = f2b(acc[mt][nt][r]);
      }
    }

  // ---- fused per-channel stats: reduce C-fragments ----
  __syncthreads();                 // done with ilds; reuse as scratch
  float* sc = (float*)ilds;        // [4 waves][64 oc][2]
  #pragma unroll
  for (int mt = 0; mt < 2; ++mt)
    #pragma unroll
    for (int r = 0; r < 16; ++r){
      float sm = 0.f, ss = 0.f;
      #pragma unroll
      for (int nt = 0; nt < 2; ++nt){
        float v = acc[mt][nt][r], v2 = v * v;
        #pragma unroll
        for (int o = 1; o < 32; o <<= 1){
          v  += __shfl_xor(v,  o, 64);
          v2 += __shfl_xor(v2, o, 64);
        }
        sm += v; ss += v2;
      }
      if (ln == 0){
        const int oc = mt * 32 + (r & 3) + 8 * (r >> 2) + 4 * half;
        sc[(wid * 64 + oc) * 2]     = sm;
        sc[(wid * 64 + oc) * 2 + 1] = ss;
      }
    }
  __syncthreads();
  if (tid < CH){
    float sm = 0.f, ss = 0.f;
    #pragma unroll
    for (int w = 0; w < 4; ++w){ sm += sc[(w * 64 + tid) * 2]; ss += sc[(w * 64 + tid) * 2 + 1]; }
    part[((size_t)tid * NBLK + blockIdx.x) * 2]     = sm;
    part[((size_t)tid * NBLK + blockIdx.x) * 2 + 1] = ss;
  }
}

template<typename TIN>
static void launch_conv(int dil, const TIN* src, const ushort* wgl,
                        const float* na, const float* nb,
                        ushort* dst, float* part, hipStream_t s){
  switch (dil){
    case 1:  convm_k<1, TIN><<<NBLK, 256, 0, s>>>(src, wgl, na, nb, dst, part); break;
    case 2:  convm_k<2, TIN><<<NBLK, 256, 0, s>>>(src, wgl, na, nb, dst, part); break;
    default: convm_k<4, TIN><<<NBLK, 256, 0, s>>>(src, wgl, na, nb, dst, part); break;
  }
}

extern "C" void kernel_launch(void* const* d_in, const int* in_sizes, int n_in,
                              void* d_out, int out_size, void* d_ws, size_t ws_size,
                              hipStream_t stream){
  const float* x1d    = (const float*)d_in[0];
  const float* x2     = (const float*)d_in[1];
  const float* W1     = (const float*)d_in[2];
  const float* g1     = (const float*)d_in[3];
  const float* b1     = (const float*)d_in[4];
  const float* W2     = (const float*)d_in[5];
  const float* res_w  = (const float*)d_in[11];
  const float* res_g  = (const float*)d_in[13];
  const float* res_be = (const float*)d_in[14];
  float* X = (float*)d_out;                    // fp32 residual stream

  float* ws = (float*)d_ws;
  ushort* A  = (ushort*)ws; ws += (size_t)CH * N2 / 2;   // bf16, 18.9 MB
  ushort* Bb = (ushort*)ws; ws += (size_t)CH * N2 / 2;   // bf16, 18.9 MB
  float* row  = ws; ws += CH * SL;
  float* col  = ws; ws += CH * SL;
  float* s1m  = ws; ws += D1;   float* s1r  = ws; ws += D1;
  float* s2m  = ws; ws += 256;  float* s2r  = ws; ws += 256;
  float* m1   = ws; ws += 64;   float* rs1  = ws; ws += 64;
  float* aA   = ws; ws += 64;   float* bA   = ws; ws += 64;
  float* aB   = ws; ws += 64;   float* bB   = ws; ws += 64;
  float* w2e  = ws; ws += D2 * CH;
  float* w3t  = ws; ws += 2 * CH * CH;
  ushort* wt  = (ushort*)ws; ws += 10 * 9 * 4 * 2 * CH * 8 / 2;  // 368640 bf16
  float* part = ws; ws += CH * NBLK * 2;

  // ---- 1d branch (x1 mean cancels downstream; rstd only)
  stats_k<float><<<dim3(1, D1), 256, 0, stream>>>(x1d, SL, part);
  stats_final_k<<<(D1 + 255) / 256, 256, 0, stream>>>(part, D1, 1, 1.f / SL, s1m, s1r);
  rowcol_k<<<2 * CH * SL / 256, 256, 0, stream>>>(x1d, W1, s1r, row, col);
  rowcol_stats_k<<<CH, 256, 0, stream>>>(row, col, m1, rs1);
  pair1n_k<<<dim3(N2 / 256, CH), 256, 0, stream>>>(row, col, m1, rs1, g1, b1, A);

  // ---- 2d branch (x2 mean cancels; rstd folds into W2)
  stats_k<float><<<dim3(16, D2), 256, 0, stream>>>(x2, N2, part);
  stats_final_k<<<1, 256, 0, stream>>>(part, D2, 16, 1.f / N2, s2m, s2r);
  w2eff_k<<<1, 64, 0, stream>>>(W2, s2r, w2e);
  gemm_pair2_k<<<N2 / 256, 256, 0, stream>>>(x2, w2e, Bb);
  stats_k<ushort><<<dim3(16, CH), 256, 0, stream>>>(Bb, N2, part);
  statsaffine_k<<<1, 64, 0, stream>>>(part, 16, 1.f / N2,
      (const float*)d_in[6], (const float*)d_in[7], 0, aA, bA);
  normleaky_k<ushort, ushort><<<dim3(N2 / 256, CH), 256, 0, stream>>>(Bb, Bb, aA, bA, nullptr);

  // ---- mix
  w3t_k<<<(2 * CH * CH + 255) / 256, 256, 0, stream>>>((const float*)d_in[8], w3t);
  gemm_mix_k<<<N2 / 256, 256, 0, stream>>>(A, Bb, w3t, X);
  stats_k<float><<<dim3(16, CH), 256, 0, stream>>>(X, N2, part);
  statsaffine_k<<<1, 64, 0, stream>>>(part, 16, 1.f / N2,
      (const float*)d_in[9], (const float*)d_in[10], 0, aA, bA);
  normleaky_k<float, float><<<dim3(N2 / 256, CH), 256, 0, stream>>>(X, X, aA, bA, nullptr);

  // ---- conv weights -> bf16 MFMA layout
  wt_k<<<368640 / 256, 256, 0, stream>>>(res_w, wt);

  // ---- 5 residual layers x 2 convs
  const int dil[5] = {1, 2, 4, 2, 1};
  for (int layer = 0; layer < 5; ++layer){
    const int d = dil[layer];
    const int li0 = layer * 2, li1 = li0 + 1;
    // conv1: X (fp32, no pre-norm) -> A raw bf16 + fused stats
    launch_conv<float>(d, X, wt + (size_t)li0 * 36864, nullptr, nullptr, A, part, stream);
    statsaffine_k<<<1, 64, 0, stream>>>(part, NBLK, 1.f / N2, res_g, res_be, li0 * CH, aA, bA);
    // conv2: A with fused norm+leaky -> Bb raw bf16 + fused stats
    launch_conv<ushort>(d, A, wt + (size_t)li1 * 36864, aA, bA, Bb, part, stream);
    statsaffine_k<<<1, 64, 0, stream>>>(part, NBLK, 1.f / N2, res_g, res_be, li1 * CH, aB, bB);
    // X = lrelu(inorm(conv2)) + X
    normleaky_k<ushort, float><<<dim3(N2 / 256, CH), 256, 0, stream>>>(Bb, X, aB, bB, X);
  }
}

// Round 6
// 1852.382 us; speedup vs baseline: 11.9353x; 1.1236x over previous
//
#include <hip/hip_runtime.h>
#include <hip/hip_bf16.h>

typedef __attribute__((ext_vector_type(8)))  short short8;
typedef __attribute__((ext_vector_type(16))) float floatx16;
typedef unsigned short ushort;

constexpr int SL  = 384;
constexpr int N2  = SL * SL;      // 147456
constexpr int CH  = 64;
constexpr int D1  = 788;
constexpr int D2  = 210;
constexpr float EPSF = 1e-5f;

constexpr int TX = 32, TY = 8;
constexpr int NBLK = (SL / TX) * (SL / TY);   // 576

__device__ __forceinline__ float lrelu(float v){ return v >= 0.f ? v : 0.01f * v; }
__device__ __forceinline__ ushort f2b(float f){
  __hip_bfloat16 h = __float2bfloat16(f); return *(ushort*)&h;
}
__device__ __forceinline__ float b2f(ushort u){
  __hip_bfloat16 h = *(__hip_bfloat16*)&u; return __bfloat162float(h);
}

__device__ __forceinline__ float wred(float v){
  #pragma unroll
  for (int o = 32; o; o >>= 1) v += __shfl_down(v, o, 64);
  return v;
}

// ---------------- per-channel stats over fp32 NCHW (x1d, x2 inputs) ----------------
__global__ void stats_k(const float* __restrict__ x, int n, float* __restrict__ part){
  const int c = blockIdx.y, s = blockIdx.x, S = gridDim.x;
  const int chunk = (n + S - 1) / S;
  const int st = s * chunk, en = min(n, st + chunk);
  const float* p = x + (size_t)c * n;
  float sm = 0.f, ss = 0.f;
  for (int i = st + threadIdx.x; i < en; i += blockDim.x){
    float v = p[i]; sm += v; ss += v * v;
  }
  sm = wred(sm); ss = wred(ss);
  __shared__ float aux[8];
  const int wid = threadIdx.x >> 6, lane = threadIdx.x & 63;
  if (lane == 0){ aux[wid] = sm; aux[4 + wid] = ss; }
  __syncthreads();
  if (threadIdx.x == 0){
    part[((size_t)c * S + s) * 2]     = aux[0] + aux[1] + aux[2] + aux[3];
    part[((size_t)c * S + s) * 2 + 1] = aux[4] + aux[5] + aux[6] + aux[7];
  }
}

__global__ void stats_final_k(const float* __restrict__ part, int C, int S, float ninv,
                              float* __restrict__ mean, float* __restrict__ rstd){
  const int c = blockIdx.x * blockDim.x + threadIdx.x;
  if (c >= C) return;
  float sm = 0.f, ss = 0.f;
  for (int s = 0; s < S; ++s){ sm += part[((size_t)c * S + s) * 2]; ss += part[((size_t)c * S + s) * 2 + 1]; }
  const float m = sm * ninv;
  mean[c] = m;
  rstd[c] = rsqrtf(ss * ninv - m * m + EPSF);
}

// finalize stats into affine (a,b): y = x*a + b
__global__ void statsaffine_k(const float* __restrict__ part, int S, float ninv,
                              const float* __restrict__ g, const float* __restrict__ be,
                              int goff, float* __restrict__ ao, float* __restrict__ bo){
  const int c = threadIdx.x;
  if (c >= CH) return;
  float sm = 0.f, ss = 0.f;
  for (int s = 0; s < S; ++s){ sm += part[((size_t)c * S + s) * 2]; ss += part[((size_t)c * S + s) * 2 + 1]; }
  const float m = sm * ninv;
  const float r = rsqrtf(ss * ninv - m * m + EPSF);
  const float a = r * g[goff + c];
  ao[c] = a;
  bo[c] = be[goff + c] - m * a;
}

// ---------------- 1d branch ----------------
__global__ void rowcol_k(const float* __restrict__ x1d, const float* __restrict__ W1,
                         const float* __restrict__ r1,
                         float* __restrict__ row, float* __restrict__ col){
  const int idx = blockIdx.x * 256 + threadIdx.x;
  const int half = idx / (CH * SL);
  const int rem  = idx % (CH * SL);
  const int c = rem / SL, l = rem % SL;
  const float* wp = W1 + (size_t)c * (2 * D1) + (size_t)half * D1;
  float acc = 0.f;
  for (int d = 0; d < D1; ++d)
    acc += wp[d] * (x1d[(size_t)d * SL + l] * r1[d]);
  (half ? col : row)[c * SL + l] = acc;
}

__global__ void rowcol_stats_k(const float* __restrict__ row, const float* __restrict__ col,
                               float* __restrict__ m1, float* __restrict__ rs1){
  const int c = blockIdx.x;
  float sr = 0, ssr = 0, sc = 0, ssc = 0;
  for (int i = threadIdx.x; i < SL; i += blockDim.x){
    float r = row[c * SL + i]; sr += r; ssr += r * r;
    float q = col[c * SL + i]; sc += q; ssc += q * q;
  }
  sr = wred(sr); ssr = wred(ssr); sc = wred(sc); ssc = wred(ssc);
  __shared__ float aux[16];
  const int wid = threadIdx.x >> 6, lane = threadIdx.x & 63;
  if (lane == 0){ aux[wid] = sr; aux[4+wid] = ssr; aux[8+wid] = sc; aux[12+wid] = ssc; }
  __syncthreads();
  if (threadIdx.x == 0){
    float a = 0, b = 0, d = 0, e = 0;
    for (int i = 0; i < 4; ++i){ a += aux[i]; b += aux[4+i]; d += aux[8+i]; e += aux[12+i]; }
    const float mr = a / SL, mc = d / SL;
    const float vr = b / SL - mr * mr, vc = e / SL - mc * mc;
    m1[c]  = mr + mc;
    rs1[c] = rsqrtf(vr + vc + EPSF);
  }
}

// fold pair1 affine into transposed row/col: rowT = row*a+b, colT = col*a   [l][c]
__global__ void rowcolT_k(const float* __restrict__ row, const float* __restrict__ col,
                          const float* __restrict__ m1, const float* __restrict__ rs1,
                          const float* __restrict__ g1, const float* __restrict__ b1,
                          float* __restrict__ rowT, float* __restrict__ colT){
  const int i = blockIdx.x * 256 + threadIdx.x;   // 384*64
  const int l = i >> 6, c = i & 63;
  const float a  = rs1[c] * g1[c];
  const float bb = b1[c] - m1[c] * a;
  rowT[i] = row[c * SL + l] * a + bb;
  colT[i] = col[c * SL + l] * a;
}

// pair1 normed -> A  (bf16 NHWC), fully coalesced
__global__ __launch_bounds__(256) void pair1n_k(const float* __restrict__ rowT,
                                                const float* __restrict__ colT,
                                                ushort* __restrict__ out){
  const size_t q = ((size_t)blockIdx.x * 256 + threadIdx.x) * 16;
  const int px = (int)(q >> 6), c0 = (int)(q & 63);
  const int i = px / SL, j = px % SL;
  const float4* rp = (const float4*)&rowT[i * 64 + c0];
  const float4* cp = (const float4*)&colT[j * 64 + c0];
  ushort o[16];
  #pragma unroll
  for (int k = 0; k < 4; ++k){
    float4 r = rp[k], cl = cp[k];
    o[4*k]   = f2b(lrelu(r.x + cl.x));
    o[4*k+1] = f2b(lrelu(r.y + cl.y));
    o[4*k+2] = f2b(lrelu(r.z + cl.z));
    o[4*k+3] = f2b(lrelu(r.w + cl.w));
  }
  *(short8*)&out[q]     = *(short8*)&o[0];
  *(short8*)&out[q + 8] = *(short8*)&o[8];
}

// ---------------- 2d branch ----------------
__global__ void w2eff_k(const float* __restrict__ W2, const float* __restrict__ r2,
                        float* __restrict__ w2e){
  const int c = threadIdx.x;
  if (c >= CH) return;
  for (int d = 0; d < D2; ++d)
    w2e[d * CH + c] = W2[(size_t)c * D2 + d] * r2[d];
}

// pair2 = w2e^T @ x2 -> Bb (bf16 NHWC) + fused per-channel stats
__global__ __launch_bounds__(256) void gemm_pair2_k(const float* __restrict__ x2,
                                                    const float* __restrict__ w2e,
                                                    ushort* __restrict__ out,
                                                    float* __restrict__ part){
  const int p = blockIdx.x * 256 + threadIdx.x;
  float acc[CH];
  #pragma unroll
  for (int c = 0; c < CH; ++c) acc[c] = 0.f;
  for (int d = 0; d < D2; ++d){
    const float xv = x2[(size_t)d * N2 + p];
    const float4* w4 = (const float4*)(w2e + d * CH);
    #pragma unroll
    for (int q = 0; q < CH / 4; ++q){
      float4 w = w4[q];
      acc[4*q] += w.x*xv; acc[4*q+1] += w.y*xv; acc[4*q+2] += w.z*xv; acc[4*q+3] += w.w*xv;
    }
  }
  ushort* op = &out[(size_t)p * 64];
  #pragma unroll
  for (int q = 0; q < 8; ++q){
    ushort o[8];
    #pragma unroll
    for (int j = 0; j < 8; ++j) o[j] = f2b(acc[q*8+j]);
    *(short8*)&op[q*8] = *(short8*)&o[0];
  }
  __shared__ float sc[4 * CH * 2];
  const int wid = threadIdx.x >> 6, lane = threadIdx.x & 63;
  #pragma unroll
  for (int c = 0; c < CH; ++c){
    float v = acc[c], v2 = acc[c]*acc[c];
    #pragma unroll
    for (int o = 1; o < 64; o <<= 1){ v += __shfl_xor(v, o, 64); v2 += __shfl_xor(v2, o, 64); }
    if (lane == 0){ sc[(wid*CH+c)*2] = v; sc[(wid*CH+c)*2+1] = v2; }
  }
  __syncthreads();
  if (threadIdx.x < CH){
    float sm = 0.f, ss = 0.f;
    #pragma unroll
    for (int w = 0; w < 4; ++w){ sm += sc[(w*CH+threadIdx.x)*2]; ss += sc[(w*CH+threadIdx.x)*2+1]; }
    part[((size_t)threadIdx.x * NBLK + blockIdx.x) * 2]     = sm;
    part[((size_t)threadIdx.x * NBLK + blockIdx.x) * 2 + 1] = ss;
  }
}

// NHWC affine+leaky in place (pair2 norm)
__global__ __launch_bounds__(256) void norm_nhwc_k(ushort* __restrict__ x,
                                                   const float* __restrict__ a,
                                                   const float* __restrict__ b){
  const size_t q = ((size_t)blockIdx.x * 256 + threadIdx.x) * 16;
  const int c0 = (int)(q & 63);
  short8 v0 = *(short8*)&x[q], v1 = *(short8*)&x[q + 8];
  ushort o[16];
  #pragma unroll
  for (int k = 0; k < 8; ++k){
    o[k]   = f2b(lrelu(b2f((ushort)v0[k]) * a[c0+k]   + b[c0+k]));
    o[k+8] = f2b(lrelu(b2f((ushort)v1[k]) * a[c0+8+k] + b[c0+8+k]));
  }
  *(short8*)&x[q]     = *(short8*)&o[0];
  *(short8*)&x[q + 8] = *(short8*)&o[8];
}

__global__ void w3t_k(const float* __restrict__ W3, float* __restrict__ w3t){
  const int i = blockIdx.x * 256 + threadIdx.x;
  if (i >= CH * 2 * CH) return;
  const int c = i / (2 * CH), e = i % (2 * CH);
  w3t[e * CH + c] = W3[i];
}

// mix = W3a@A + W3b@Bb (NHWC bf16 in/out) + fused stats
__global__ __launch_bounds__(256) void gemm_mix_k(const ushort* __restrict__ A,
                                                  const ushort* __restrict__ B,
                                                  const float* __restrict__ w3t,
                                                  ushort* __restrict__ out,
                                                  float* __restrict__ part){
  const int p = blockIdx.x * 256 + threadIdx.x;
  float acc[CH];
  #pragma unroll
  for (int c = 0; c < CH; ++c) acc[c] = 0.f;
  ushort av[CH];
  const ushort* ap = &A[(size_t)p * 64];
  #pragma unroll
  for (int q = 0; q < 8; ++q) *(short8*)&av[q*8] = *(const short8*)&ap[q*8];
  for (int e = 0; e < CH; ++e){
    const float xv = b2f(av[e]);
    const float4* w4 = (const float4*)(w3t + e * CH);
    #pragma unroll
    for (int q = 0; q < CH / 4; ++q){
      float4 w = w4[q];
      acc[4*q] += w.x*xv; acc[4*q+1] += w.y*xv; acc[4*q+2] += w.z*xv; acc[4*q+3] += w.w*xv;
    }
  }
  const ushort* bp = &B[(size_t)p * 64];
  #pragma unroll
  for (int q = 0; q < 8; ++q) *(short8*)&av[q*8] = *(const short8*)&bp[q*8];
  for (int e = 0; e < CH; ++e){
    const float xv = b2f(av[e]);
    const float4* w4 = (const float4*)(w3t + (CH + e) * CH);
    #pragma unroll
    for (int q = 0; q < CH / 4; ++q){
      float4 w = w4[q];
      acc[4*q] += w.x*xv; acc[4*q+1] += w.y*xv; acc[4*q+2] += w.z*xv; acc[4*q+3] += w.w*xv;
    }
  }
  ushort* op = &out[(size_t)p * 64];
  #pragma unroll
  for (int q = 0; q < 8; ++q){
    ushort o[8];
    #pragma unroll
    for (int j = 0; j < 8; ++j) o[j] = f2b(acc[q*8+j]);
    *(short8*)&op[q*8] = *(short8*)&o[0];
  }
  __shared__ float sc[4 * CH * 2];
  const int wid = threadIdx.x >> 6, lane = threadIdx.x & 63;
  #pragma unroll
  for (int c = 0; c < CH; ++c){
    float v = acc[c], v2 = acc[c]*acc[c];
    #pragma unroll
    for (int o = 1; o < 64; o <<= 1){ v += __shfl_xor(v, o, 64); v2 += __shfl_xor(v2, o, 64); }
    if (lane == 0){ sc[(wid*CH+c)*2] = v; sc[(wid*CH+c)*2+1] = v2; }
  }
  __syncthreads();
  if (threadIdx.x < CH){
    float sm = 0.f, ss = 0.f;
    #pragma unroll
    for (int w = 0; w < 4; ++w){ sm += sc[(w*CH+threadIdx.x)*2]; ss += sc[(w*CH+threadIdx.x)*2+1]; }
    part[((size_t)threadIdx.x * NBLK + blockIdx.x) * 2]     = sm;
    part[((size_t)threadIdx.x * NBLK + blockIdx.x) * 2 + 1] = ss;
  }
}

// ---------------- norm + residual add; X fp32 NCHW (d_out), Xb bf16 NHWC ----------------
// per block: 64 pixels x 64 channels, transpose via LDS both directions
__global__ __launch_bounds__(256) void norm_res_k(const ushort* __restrict__ src,
                                                  const float* __restrict__ a,
                                                  const float* __restrict__ b,
                                                  float* __restrict__ X,
                                                  ushort* __restrict__ Xb,
                                                  int doRes){
  __shared__ float tf[64 * 68];
  const int tid = threadIdx.x;
  const int p0 = blockIdx.x * 64;
  const int pxl = tid >> 2, c0 = (tid & 3) * 16;
  // phase 1: read NHWC + affine + leaky -> LDS [c][px]
  {
    const ushort* sp = &src[(size_t)(p0 + pxl) * 64 + c0];
    short8 v0 = *(const short8*)&sp[0], v1 = *(const short8*)&sp[8];
    #pragma unroll
    for (int k = 0; k < 8; ++k){
      tf[(c0+k)*68 + pxl]   = lrelu(b2f((ushort)v0[k]) * a[c0+k]   + b[c0+k]);
      tf[(c0+8+k)*68 + pxl] = lrelu(b2f((ushort)v1[k]) * a[c0+8+k] + b[c0+8+k]);
    }
  }
  __syncthreads();
  // phase 2: add residual (fp32 NCHW), write X, leave fp32 in LDS
  {
    const int c = tid >> 2, part = tid & 3;
    const size_t gb = (size_t)c * N2 + p0 + part * 16;
    float w[16];
    #pragma unroll
    for (int k = 0; k < 16; ++k) w[k] = tf[c*68 + part*16 + k];
    if (doRes){
      #pragma unroll
      for (int k = 0; k < 16; ++k) w[k] += X[gb + k];
      #pragma unroll
      for (int k = 0; k < 16; ++k) tf[c*68 + part*16 + k] = w[k];
    }
    #pragma unroll
    for (int k = 0; k < 16; ++k) X[gb + k] = w[k];
  }
  __syncthreads();
  // phase 3: LDS -> bf16 NHWC Xb
  {
    ushort o[16];
    #pragma unroll
    for (int k = 0; k < 16; ++k) o[k] = f2b(tf[(c0+k)*68 + pxl]);
    ushort* xp = &Xb[(size_t)(p0 + pxl) * 64 + c0];
    *(short8*)&xp[0] = *(short8*)&o[0];
    *(short8*)&xp[8] = *(short8*)&o[8];
  }
}

// conv weights [conv][oc][ic][3][3] fp32 -> bf16 [conv][tap][kc][half][oc][8j]
__global__ void wt_k(const float* __restrict__ w, ushort* __restrict__ wt){
  const int i = blockIdx.x * 256 + threadIdx.x;   // 368640
  const int j    = i & 7;
  const int oc   = (i >> 3) & 63;
  const int half = (i >> 9) & 1;
  const int kc   = (i >> 10) & 3;
  const int tap  = (i / 4096) % 9;
  const int cv   = i / 36864;
  const int ic   = kc * 16 + half * 8 + j;
  wt[i] = f2b(w[((size_t)(cv * CH + oc) * CH + ic) * 9 + tap]);
}

// ---------------- MFMA conv, NHWC in/out, 2-phase K-split, fused stats ----------------
template<int DIL>
__global__ __launch_bounds__(256, 4) void convm_k(const ushort* __restrict__ in,
                                                  const ushort* __restrict__ wg,
                                                  const float* __restrict__ na,
                                                  const float* __restrict__ nb,
                                                  ushort* __restrict__ out,
                                                  float* __restrict__ part){
  constexpr int TWd = TX + 2 * DIL, THd = TY + 2 * DIL, NSLOT = TWd * THd;
  constexpr int EPIB = 256 * 136 + 4 * CH * 2 * 4;   // transpose buf + stats scratch
  constexpr int LDSB = (NSLOT * 64 > EPIB) ? NSLOT * 64 : EPIB;
  __shared__ __align__(16) unsigned char ldsraw[LDSB];
  ushort* st = (ushort*)ldsraw;

  const int tid = threadIdx.x;
  const int bx = blockIdx.x % (SL / TX), by = blockIdx.x / (SL / TX);
  const int x0 = bx * TX - DIL, y0 = by * TY - DIL;
  const int lane = tid & 63, wid = tid >> 6;
  const int ln = lane & 31, half = lane >> 5;
  const int ch = tid & 3;                     // fixed 8-ic chunk per thread (staging)
  const bool donorm = (na != nullptr);

  floatx16 acc[2][2];
  #pragma unroll
  for (int mt = 0; mt < 2; ++mt)
    #pragma unroll
    for (int nt = 0; nt < 2; ++nt)
      #pragma unroll
      for (int r = 0; r < 16; ++r) acc[mt][nt][r] = 0.f;

  for (int P = 0; P < 2; ++P){
    if (P) __syncthreads();                   // protect st before restage
    float sa[8], sb[8];
    if (donorm){
      #pragma unroll
      for (int j = 0; j < 8; ++j){ sa[j] = na[P*32 + ch*8 + j]; sb[j] = nb[P*32 + ch*8 + j]; }
    }
    for (int q = tid; q < NSLOT * 4; q += 256){
      const int slot = q >> 2;
      const int sy = slot / TWd, sx = slot % TWd;
      const int gx = x0 + sx, gy = y0 + sy;
      short8 v8;
      if (((unsigned)gx < (unsigned)SL) && ((unsigned)gy < (unsigned)SL)){
        v8 = *(const short8*)&in[((size_t)(gy * SL + gx)) * 64 + P*32 + ch*8];
        if (donorm){
          #pragma unroll
          for (int j = 0; j < 8; ++j)
            v8[j] = (short)f2b(lrelu(b2f((ushort)v8[j]) * sa[j] + sb[j]));
        }
      } else {
        #pragma unroll
        for (int j = 0; j < 8; ++j) v8[j] = 0;
      }
      *(short8*)&st[slot * 32 + ((ch ^ ((slot >> 1) & 3)) << 3)] = v8;
    }
    __syncthreads();
    #pragma unroll
    for (int tap = 0; tap < 9; ++tap){
      const int ky = tap / 3, kx = tap % 3;
      const int s0 = (2*wid + ky*DIL) * TWd + ln + kx*DIL;
      const int s1 = s0 + TWd;
      #pragma unroll
      for (int kcl = 0; kcl < 2; ++kcl){
        const int kc = 2*P + kcl;
        const int chb = kcl * 2 + half;
        const ushort* ab = wg + ((size_t)((tap*4 + kc)*2 + half)) * 512;
        short8 a0 = *(const short8*)&ab[ln * 8];
        short8 a1 = *(const short8*)&ab[256 + ln * 8];
        short8 b0 = *(const short8*)&st[s0*32 + ((chb ^ ((s0 >> 1) & 3)) << 3)];
        short8 b1 = *(const short8*)&st[s1*32 + ((chb ^ ((s1 >> 1) & 3)) << 3)];
        acc[0][0] = __builtin_amdgcn_mfma_f32_32x32x16_bf16(a0, b0, acc[0][0], 0, 0, 0);
        acc[1][0] = __builtin_amdgcn_mfma_f32_32x32x16_bf16(a1, b0, acc[1][0], 0, 0, 0);
        acc[0][1] = __builtin_amdgcn_mfma_f32_32x32x16_bf16(a0, b1, acc[0][1], 0, 0, 0);
        acc[1][1] = __builtin_amdgcn_mfma_f32_32x32x16_bf16(a1, b1, acc[1][1], 0, 0, 0);
      }
    }
  }

  // ---- epilogue: transpose C to [px][oc] via LDS, coalesced NHWC stores ----
  __syncthreads();
  ushort* tb = (ushort*)ldsraw;               // [256 px][68 ushorts] (136 B rows)
  float*  sc = (float*)(ldsraw + 256 * 136);  // [4][64][2]
  #pragma unroll
  for (int mt = 0; mt < 2; ++mt)
    #pragma unroll
    for (int nt = 0; nt < 2; ++nt){
      const int pxl = (2*wid + nt) * 32 + ln;
      #pragma unroll
      for (int rq = 0; rq < 4; ++rq){
        const int oc0 = mt*32 + 8*rq + 4*half;
        #pragma unroll
        for (int k = 0; k < 2; ++k){
          const int r = rq*4 + k*2;
          unsigned pk = (unsigned)f2b(acc[mt][nt][r]) | ((unsigned)f2b(acc[mt][nt][r+1]) << 16);
          *(unsigned*)&tb[pxl * 68 + oc0 + k*2] = pk;
        }
      }
    }
  // fused stats from accs
  #pragma unroll
  for (int mt = 0; mt < 2; ++mt)
    #pragma unroll
    for (int rq = 0; rq < 4; ++rq)
      #pragma unroll
      for (int t = 0; t < 4; ++t){
        const int r = rq*4 + t;
        float v  = acc[mt][0][r] + acc[mt][1][r];
        float v2 = acc[mt][0][r]*acc[mt][0][r] + acc[mt][1][r]*acc[mt][1][r];
        #pragma unroll
        for (int o = 1; o < 32; o <<= 1){ v += __shfl_xor(v, o, 64); v2 += __shfl_xor(v2, o, 64); }
        if (ln == 0){
          const int oc = mt*32 + 8*rq + 4*half + t;
          sc[(wid*CH + oc)*2] = v; sc[(wid*CH + oc)*2 + 1] = v2;
        }
      }
  __syncthreads();
  // stores: wave handles 2 tile rows; lane -> 64B chunk
  {
    const int px = lane >> 1, pt = lane & 1;
    #pragma unroll
    for (int nt = 0; nt < 2; ++nt){
      const int row = 2*wid + nt;
      const int gy = by*TY + row;
      const ushort* sp = &tb[(row*32 + px) * 68 + pt*32];
      ushort* dp = &out[((size_t)(gy * SL) + bx*TX + px) * 64 + pt*32];
      #pragma unroll
      for (int k = 0; k < 4; ++k){
        uint2 v = *(const uint2*)&sp[k*4];
        *(uint2*)&dp[k*4] = v;
      }
      #pragma unroll
      for (int k = 4; k < 8; ++k){
        uint2 v = *(const uint2*)&sp[k*4];
        *(uint2*)&dp[k*4] = v;
      }
    }
  }
  if (tid < CH){
    float sm = 0.f, ss = 0.f;
    #pragma unroll
    for (int w = 0; w < 4; ++w){ sm += sc[(w*CH + tid)*2]; ss += sc[(w*CH + tid)*2 + 1]; }
    part[((size_t)tid * NBLK + blockIdx.x) * 2]     = sm;
    part[((size_t)tid * NBLK + blockIdx.x) * 2 + 1] = ss;
  }
}

static void launch_conv(int dil, const ushort* src, const ushort* wgl,
                        const float* na, const float* nb,
                        ushort* dst, float* part, hipStream_t s){
  switch (dil){
    case 1:  convm_k<1><<<NBLK, 256, 0, s>>>(src, wgl, na, nb, dst, part); break;
    case 2:  convm_k<2><<<NBLK, 256, 0, s>>>(src, wgl, na, nb, dst, part); break;
    default: convm_k<4><<<NBLK, 256, 0, s>>>(src, wgl, na, nb, dst, part); break;
  }
}

extern "C" void kernel_launch(void* const* d_in, const int* in_sizes, int n_in,
                              void* d_out, int out_size, void* d_ws, size_t ws_size,
                              hipStream_t stream){
  const float* x1d    = (const float*)d_in[0];
  const float* x2     = (const float*)d_in[1];
  const float* W1     = (const float*)d_in[2];
  const float* g1     = (const float*)d_in[3];
  const float* b1     = (const float*)d_in[4];
  const float* W2     = (const float*)d_in[5];
  const float* res_w  = (const float*)d_in[11];
  const float* res_g  = (const float*)d_in[13];
  const float* res_be = (const float*)d_in[14];
  float* X = (float*)d_out;                        // fp32 NCHW residual stream

  unsigned char* wp = (unsigned char*)d_ws;
  ushort* A  = (ushort*)wp; wp += (size_t)N2 * 64 * 2;
  ushort* Bb = (ushort*)wp; wp += (size_t)N2 * 64 * 2;
  ushort* Xb = (ushort*)wp; wp += (size_t)N2 * 64 * 2;
  ushort* wt = (ushort*)wp; wp += (size_t)368640 * 2;
  float* fw = (float*)wp;
  float* row  = fw; fw += CH * SL;
  float* col  = fw; fw += CH * SL;
  float* rowT = fw; fw += SL * CH;
  float* colT = fw; fw += SL * CH;
  float* s1m  = fw; fw += D1;   float* s1r = fw; fw += D1;
  float* s2m  = fw; fw += 256;  float* s2r = fw; fw += 256;
  float* m1   = fw; fw += 64;   float* rs1 = fw; fw += 64;
  float* aA   = fw; fw += 64;   float* bA  = fw; fw += 64;
  float* aB   = fw; fw += 64;   float* bB  = fw; fw += 64;
  float* w2e  = fw; fw += D2 * CH;
  float* w3t  = fw; fw += 2 * CH * CH;
  float* part = fw; fw += CH * NBLK * 2;

  // ---- 1d branch
  stats_k<<<dim3(1, D1), 256, 0, stream>>>(x1d, SL, part);
  stats_final_k<<<(D1 + 255) / 256, 256, 0, stream>>>(part, D1, 1, 1.f / SL, s1m, s1r);
  rowcol_k<<<2 * CH * SL / 256, 256, 0, stream>>>(x1d, W1, s1r, row, col);
  rowcol_stats_k<<<CH, 256, 0, stream>>>(row, col, m1, rs1);
  rowcolT_k<<<SL * CH / 256, 256, 0, stream>>>(row, col, m1, rs1, g1, b1, rowT, colT);
  pair1n_k<<<N2 * 64 / 4096, 256, 0, stream>>>(rowT, colT, A);

  // ---- 2d branch
  stats_k<<<dim3(16, D2), 256, 0, stream>>>(x2, N2, part);
  stats_final_k<<<1, 256, 0, stream>>>(part, D2, 16, 1.f / N2, s2m, s2r);
  w2eff_k<<<1, 64, 0, stream>>>(W2, s2r, w2e);
  gemm_pair2_k<<<NBLK, 256, 0, stream>>>(x2, w2e, Bb, part);
  statsaffine_k<<<1, 64, 0, stream>>>(part, NBLK, 1.f / N2,
      (const float*)d_in[6], (const float*)d_in[7], 0, aA, bA);
  norm_nhwc_k<<<N2 * 64 / 4096, 256, 0, stream>>>(Bb, aA, bA);

  // ---- mix -> Xb (bf16 NHWC) + stats; bootstrap X (fp32 NCHW) via norm_res
  w3t_k<<<(2 * CH * CH + 255) / 256, 256, 0, stream>>>((const float*)d_in[8], w3t);
  gemm_mix_k<<<NBLK, 256, 0, stream>>>(A, Bb, w3t, Xb, part);
  statsaffine_k<<<1, 64, 0, stream>>>(part, NBLK, 1.f / N2,
      (const float*)d_in[9], (const float*)d_in[10], 0, aA, bA);
  norm_res_k<<<N2 / 64, 256, 0, stream>>>(Xb, aA, bA, X, Xb, 0);

  // ---- conv weights
  wt_k<<<368640 / 256, 256, 0, stream>>>(res_w, wt);

  // ---- 5 residual layers x 2 convs
  const int dil[5] = {1, 2, 4, 2, 1};
  for (int layer = 0; layer < 5; ++layer){
    const int d = dil[layer];
    const int li0 = layer * 2, li1 = li0 + 1;
    launch_conv(d, Xb, wt + (size_t)li0 * 36864, nullptr, nullptr, A, part, stream);
    statsaffine_k<<<1, 64, 0, stream>>>(part, NBLK, 1.f / N2, res_g, res_be, li0 * CH, aA, bA);
    launch_conv(d, A, wt + (size_t)li1 * 36864, aA, bA, Bb, part, stream);
    statsaffine_k<<<1, 64, 0, stream>>>(part, NBLK, 1.f / N2, res_g, res_be, li1 * CH, aB, bB);
    norm_res_k<<<N2 / 64, 256, 0, stream>>>(Bb, aB, bB, X, Xb, 1);
  }
}

// Round 7
// 1776.336 us; speedup vs baseline: 12.4463x; 1.0428x over previous
//
#include <hip/hip_runtime.h>
#include <hip/hip_bf16.h>

typedef __attribute__((ext_vector_type(8)))  short short8;
typedef __attribute__((ext_vector_type(16))) float floatx16;
typedef unsigned short ushort;

constexpr int SL  = 384;
constexpr int N2  = SL * SL;      // 147456
constexpr int CH  = 64;
constexpr int D1  = 788;
constexpr int D2  = 210;
constexpr float EPSF = 1e-5f;

constexpr int TX = 32, TY = 8;
constexpr int NBLK = (SL / TX) * (SL / TY);   // 576

__device__ __forceinline__ float lrelu(float v){ return v >= 0.f ? v : 0.01f * v; }
__device__ __forceinline__ ushort f2b(float f){
  __hip_bfloat16 h = __float2bfloat16(f); return *(ushort*)&h;
}
__device__ __forceinline__ float b2f(ushort u){
  __hip_bfloat16 h = *(__hip_bfloat16*)&u; return __bfloat162float(h);
}

__device__ __forceinline__ float wred(float v){
  #pragma unroll
  for (int o = 32; o; o >>= 1) v += __shfl_down(v, o, 64);
  return v;
}

// ---------------- per-channel stats over fp32 NCHW ----------------
__global__ void stats_k(const float* __restrict__ x, int n, float* __restrict__ part){
  const int c = blockIdx.y, s = blockIdx.x, S = gridDim.x;
  const int chunk = (n + S - 1) / S;
  const int st = s * chunk, en = min(n, st + chunk);
  const float* p = x + (size_t)c * n;
  float sm = 0.f, ss = 0.f;
  for (int i = st + threadIdx.x; i < en; i += blockDim.x){
    float v = p[i]; sm += v; ss += v * v;
  }
  sm = wred(sm); ss = wred(ss);
  __shared__ float aux[8];
  const int wid = threadIdx.x >> 6, lane = threadIdx.x & 63;
  if (lane == 0){ aux[wid] = sm; aux[4 + wid] = ss; }
  __syncthreads();
  if (threadIdx.x == 0){
    part[((size_t)c * S + s) * 2]     = aux[0] + aux[1] + aux[2] + aux[3];
    part[((size_t)c * S + s) * 2 + 1] = aux[4] + aux[5] + aux[6] + aux[7];
  }
}

__global__ void stats_final_k(const float* __restrict__ part, int C, int S, float ninv,
                              float* __restrict__ mean, float* __restrict__ rstd){
  const int c = blockIdx.x * blockDim.x + threadIdx.x;
  if (c >= C) return;
  float sm = 0.f, ss = 0.f;
  for (int s = 0; s < S; ++s){ sm += part[((size_t)c * S + s) * 2]; ss += part[((size_t)c * S + s) * 2 + 1]; }
  const float m = sm * ninv;
  mean[c] = m;
  rstd[c] = rsqrtf(ss * ninv - m * m + EPSF);
}

__global__ void statsaffine_k(const float* __restrict__ part, int S, float ninv,
                              const float* __restrict__ g, const float* __restrict__ be,
                              int goff, float* __restrict__ ao, float* __restrict__ bo){
  const int c = threadIdx.x;
  if (c >= CH) return;
  float sm = 0.f, ss = 0.f;
  for (int s = 0; s < S; ++s){ sm += part[((size_t)c * S + s) * 2]; ss += part[((size_t)c * S + s) * 2 + 1]; }
  const float m = sm * ninv;
  const float r = rsqrtf(ss * ninv - m * m + EPSF);
  const float a = r * g[goff + c];
  ao[c] = a;
  bo[c] = be[goff + c] - m * a;
}

// ---------------- 1d branch (D1 split x4 for occupancy) ----------------
__global__ void rowcol_k(const float* __restrict__ x1d, const float* __restrict__ W1,
                         const float* __restrict__ r1, float* __restrict__ rcP){
  const int idx = blockIdx.x * 256 + threadIdx.x;   // (half, c, l)
  const int chunk = blockIdx.y;
  const int half = idx / (CH * SL);
  const int rem  = idx % (CH * SL);
  const int c = rem / SL, l = rem % SL;
  const int d0 = chunk * 197, d1 = min(D1, d0 + 197);
  const float* wp = W1 + (size_t)c * (2 * D1) + (size_t)half * D1;
  float acc = 0.f;
  for (int d = d0; d < d1; ++d)
    acc += wp[d] * (x1d[(size_t)d * SL + l] * r1[d]);
  rcP[(size_t)chunk * (2 * CH * SL) + idx] = acc;
}

__global__ void rowcol_stats_k(const float* __restrict__ rcP,
                               float* __restrict__ m1, float* __restrict__ rs1){
  const int c = blockIdx.x;
  float sr = 0, ssr = 0, sc = 0, ssc = 0;
  for (int i = threadIdx.x; i < SL; i += blockDim.x){
    float r = 0, q = 0;
    #pragma unroll
    for (int k = 0; k < 4; ++k){
      r += rcP[(size_t)k * (2*CH*SL) + c * SL + i];
      q += rcP[(size_t)k * (2*CH*SL) + CH*SL + c * SL + i];
    }
    sr += r; ssr += r * r; sc += q; ssc += q * q;
  }
  sr = wred(sr); ssr = wred(ssr); sc = wred(sc); ssc = wred(ssc);
  __shared__ float aux[16];
  const int wid = threadIdx.x >> 6, lane = threadIdx.x & 63;
  if (lane == 0){ aux[wid] = sr; aux[4+wid] = ssr; aux[8+wid] = sc; aux[12+wid] = ssc; }
  __syncthreads();
  if (threadIdx.x == 0){
    float a = 0, b = 0, d = 0, e = 0;
    for (int i = 0; i < 4; ++i){ a += aux[i]; b += aux[4+i]; d += aux[8+i]; e += aux[12+i]; }
    const float mr = a / SL, mc = d / SL;
    const float vr = b / SL - mr * mr, vc = e / SL - mc * mc;
    m1[c]  = mr + mc;
    rs1[c] = rsqrtf(vr + vc + EPSF);
  }
}

__global__ void rowcolT_k(const float* __restrict__ rcP,
                          const float* __restrict__ m1, const float* __restrict__ rs1,
                          const float* __restrict__ g1, const float* __restrict__ b1,
                          float* __restrict__ rowT, float* __restrict__ colT){
  const int i = blockIdx.x * 256 + threadIdx.x;   // 384*64
  const int l = i >> 6, c = i & 63;
  float r = 0, q = 0;
  #pragma unroll
  for (int k = 0; k < 4; ++k){
    r += rcP[(size_t)k * (2*CH*SL) + c * SL + l];
    q += rcP[(size_t)k * (2*CH*SL) + CH*SL + c * SL + l];
  }
  const float a  = rs1[c] * g1[c];
  const float bb = b1[c] - m1[c] * a;
  rowT[i] = r * a + bb;
  colT[i] = q * a;
}

__global__ __launch_bounds__(256) void pair1n_k(const float* __restrict__ rowT,
                                                const float* __restrict__ colT,
                                                ushort* __restrict__ out){
  const size_t q = ((size_t)blockIdx.x * 256 + threadIdx.x) * 16;
  const int px = (int)(q >> 6), c0 = (int)(q & 63);
  const int i = px / SL, j = px % SL;
  const float4* rp = (const float4*)&rowT[i * 64 + c0];
  const float4* cp = (const float4*)&colT[j * 64 + c0];
  ushort o[16];
  #pragma unroll
  for (int k = 0; k < 4; ++k){
    float4 r = rp[k], cl = cp[k];
    o[4*k]   = f2b(lrelu(r.x + cl.x));
    o[4*k+1] = f2b(lrelu(r.y + cl.y));
    o[4*k+2] = f2b(lrelu(r.z + cl.z));
    o[4*k+3] = f2b(lrelu(r.w + cl.w));
  }
  *(short8*)&out[q]     = *(short8*)&o[0];
  *(short8*)&out[q + 8] = *(short8*)&o[8];
}

// ---------------- 2d branch: oc-split VALU GEMM + fused stats ----------------
__global__ void w2eff_k(const float* __restrict__ W2, const float* __restrict__ r2,
                        float* __restrict__ w2e){
  const int c = threadIdx.x;
  if (c >= CH) return;
  for (int d = 0; d < D2; ++d)
    w2e[d * CH + c] = W2[(size_t)c * D2 + d] * r2[d];
}

__global__ __launch_bounds__(256) void pair2v_k(const float* __restrict__ x2,
                                                const float* __restrict__ w2e,
                                                ushort* __restrict__ out,
                                                float* __restrict__ part){
  const int p = blockIdx.x * 256 + threadIdx.x;
  const int oh = blockIdx.y;                    // oc half: 0 or 1
  float acc[32];
  #pragma unroll
  for (int c = 0; c < 32; ++c) acc[c] = 0.f;
  for (int d = 0; d < D2; ++d){
    const float xv = x2[(size_t)d * N2 + p];
    const float4* w4 = (const float4*)(w2e + d * CH + oh * 32);
    #pragma unroll
    for (int q = 0; q < 8; ++q){
      float4 w = w4[q];
      acc[4*q] += w.x*xv; acc[4*q+1] += w.y*xv; acc[4*q+2] += w.z*xv; acc[4*q+3] += w.w*xv;
    }
  }
  ushort* op = &out[(size_t)p * 64 + oh * 32];
  #pragma unroll
  for (int q = 0; q < 4; ++q){
    ushort o[8];
    #pragma unroll
    for (int j = 0; j < 8; ++j) o[j] = f2b(acc[q*8+j]);
    *(short8*)&op[q*8] = *(short8*)&o[0];
  }
  __shared__ float sc[4 * 32 * 2];
  const int wid = threadIdx.x >> 6, lane = threadIdx.x & 63;
  #pragma unroll
  for (int c = 0; c < 32; ++c){
    float v = acc[c], v2 = acc[c]*acc[c];
    #pragma unroll
    for (int o = 1; o < 64; o <<= 1){ v += __shfl_xor(v, o, 64); v2 += __shfl_xor(v2, o, 64); }
    if (lane == 0){ sc[(wid*32+c)*2] = v; sc[(wid*32+c)*2+1] = v2; }
  }
  __syncthreads();
  if (threadIdx.x < 32){
    float sm = 0.f, ss = 0.f;
    #pragma unroll
    for (int w = 0; w < 4; ++w){ sm += sc[(w*32+threadIdx.x)*2]; ss += sc[(w*32+threadIdx.x)*2+1]; }
    const int oc = oh * 32 + threadIdx.x;
    part[((size_t)oc * NBLK + blockIdx.x) * 2]     = sm;
    part[((size_t)oc * NBLK + blockIdx.x) * 2 + 1] = ss;
  }
}

// NHWC affine+leaky in place
__global__ __launch_bounds__(256) void norm_nhwc_k(ushort* __restrict__ x,
                                                   const float* __restrict__ a,
                                                   const float* __restrict__ b){
  const size_t q = ((size_t)blockIdx.x * 256 + threadIdx.x) * 16;
  const int c0 = (int)(q & 63);
  short8 v0 = *(short8*)&x[q], v1 = *(short8*)&x[q + 8];
  ushort o[16];
  #pragma unroll
  for (int k = 0; k < 8; ++k){
    o[k]   = f2b(lrelu(b2f((ushort)v0[k]) * a[c0+k]   + b[c0+k]));
    o[k+8] = f2b(lrelu(b2f((ushort)v1[k]) * a[c0+8+k] + b[c0+8+k]));
  }
  *(short8*)&x[q]     = *(short8*)&o[0];
  *(short8*)&x[q + 8] = *(short8*)&o[8];
}

// W3 [c][2CH] fp32 -> bf16 A-operand layout [kc(8)][half(2)][oc(64)][j(8)]
__global__ void w3b_k(const float* __restrict__ W3, ushort* __restrict__ w3b){
  const int i = blockIdx.x * 256 + threadIdx.x;   // 8192
  const int j    = i & 7;
  const int oc   = (i >> 3) & 63;
  const int half = (i >> 9) & 1;
  const int kc   = i >> 10;
  const int e    = kc * 16 + half * 8 + j;
  w3b[i] = f2b(W3[oc * (2 * CH) + e]);
}

// ---------------- MFMA mix: K=128 (A || Bb), direct-global B, in-place out ----------------
__global__ __launch_bounds__(256) void mixm_k(const ushort* __restrict__ A,
                                              const ushort* __restrict__ Bv,
                                              const ushort* __restrict__ w3b,
                                              ushort* __restrict__ out,
                                              float* __restrict__ part){
  __shared__ __align__(16) unsigned char ldsraw[256 * 136 + 4 * CH * 2 * 4];
  const int tid = threadIdx.x, lane = tid & 63, wid = tid >> 6;
  const int ln = lane & 31, half = lane >> 5;
  const int px0 = blockIdx.x * 256;
  floatx16 acc[2][2];
  #pragma unroll
  for (int mt = 0; mt < 2; ++mt)
    #pragma unroll
    for (int nt = 0; nt < 2; ++nt)
      #pragma unroll
      for (int r = 0; r < 16; ++r) acc[mt][nt][r] = 0.f;

  const size_t rb0 = ((size_t)(px0 + wid * 64 + ln)) * 64;
  const size_t rb1 = rb0 + (size_t)32 * 64;
  #pragma unroll
  for (int kc = 0; kc < 8; ++kc){
    const ushort* src = (kc < 4) ? A : Bv;
    const int co = (kc & 3) * 16 + half * 8;
    const ushort* ab = w3b + ((size_t)(kc * 2 + half)) * 512;
    short8 a0 = *(const short8*)&ab[ln * 8];
    short8 a1 = *(const short8*)&ab[256 + ln * 8];
    short8 b0 = *(const short8*)&src[rb0 + co];
    short8 b1 = *(const short8*)&src[rb1 + co];
    acc[0][0] = __builtin_amdgcn_mfma_f32_32x32x16_bf16(a0, b0, acc[0][0], 0, 0, 0);
    acc[1][0] = __builtin_amdgcn_mfma_f32_32x32x16_bf16(a1, b0, acc[1][0], 0, 0, 0);
    acc[0][1] = __builtin_amdgcn_mfma_f32_32x32x16_bf16(a0, b1, acc[0][1], 0, 0, 0);
    acc[1][1] = __builtin_amdgcn_mfma_f32_32x32x16_bf16(a1, b1, acc[1][1], 0, 0, 0);
  }

  // epilogue: transpose to [px][oc] via LDS, NHWC stores + fused stats
  ushort* tb = (ushort*)ldsraw;
  float*  sc = (float*)(ldsraw + 256 * 136);
  #pragma unroll
  for (int mt = 0; mt < 2; ++mt)
    #pragma unroll
    for (int nt = 0; nt < 2; ++nt){
      const int pxl = (2*wid + nt) * 32 + ln;
      #pragma unroll
      for (int rq = 0; rq < 4; ++rq){
        const int oc0 = mt*32 + 8*rq + 4*half;
        #pragma unroll
        for (int k = 0; k < 2; ++k){
          const int r = rq*4 + k*2;
          unsigned pk = (unsigned)f2b(acc[mt][nt][r]) | ((unsigned)f2b(acc[mt][nt][r+1]) << 16);
          *(unsigned*)&tb[pxl * 68 + oc0 + k*2] = pk;
        }
      }
    }
  #pragma unroll
  for (int mt = 0; mt < 2; ++mt)
    #pragma unroll
    for (int rq = 0; rq < 4; ++rq)
      #pragma unroll
      for (int t = 0; t < 4; ++t){
        const int r = rq*4 + t;
        float v  = acc[mt][0][r] + acc[mt][1][r];
        float v2 = acc[mt][0][r]*acc[mt][0][r] + acc[mt][1][r]*acc[mt][1][r];
        #pragma unroll
        for (int o = 1; o < 32; o <<= 1){ v += __shfl_xor(v, o, 64); v2 += __shfl_xor(v2, o, 64); }
        if (ln == 0){
          const int oc = mt*32 + 8*rq + 4*half + t;
          sc[(wid*CH + oc)*2] = v; sc[(wid*CH + oc)*2 + 1] = v2;
        }
      }
  __syncthreads();
  {
    const int px = lane >> 1, pt = lane & 1;
    #pragma unroll
    for (int nt = 0; nt < 2; ++nt){
      const int rr = 2*wid + nt;
      const ushort* sp = &tb[(rr*32 + px) * 68 + pt*32];
      ushort* dp = &out[((size_t)(px0 + rr*32 + px)) * 64 + pt*32];
      #pragma unroll
      for (int k = 0; k < 8; ++k){
        uint2 v = *(const uint2*)&sp[k*4];
        *(uint2*)&dp[k*4] = v;
      }
    }
  }
  if (tid < CH){
    float sm = 0.f, ss = 0.f;
    #pragma unroll
    for (int w = 0; w < 4; ++w){ sm += sc[(w*CH + tid)*2]; ss += sc[(w*CH + tid)*2 + 1]; }
    part[((size_t)tid * NBLK + blockIdx.x) * 2]     = sm;
    part[((size_t)tid * NBLK + blockIdx.x) * 2 + 1] = ss;
  }
}

// ---------------- norm + residual; X fp32 NCHW (d_out), Xb bf16 NHWC ----------------
__global__ __launch_bounds__(256) void norm_res_k(const ushort* __restrict__ src,
                                                  const float* __restrict__ a,
                                                  const float* __restrict__ b,
                                                  float* __restrict__ X,
                                                  ushort* __restrict__ Xb,
                                                  int doRes){
  __shared__ float tf[64 * 68];
  const int tid = threadIdx.x;
  const int p0 = blockIdx.x * 64;
  const int pxl = tid >> 2, c0 = (tid & 3) * 16;
  {
    const ushort* sp = &src[(size_t)(p0 + pxl) * 64 + c0];
    short8 v0 = *(const short8*)&sp[0], v1 = *(const short8*)&sp[8];
    #pragma unroll
    for (int k = 0; k < 8; ++k){
      tf[(c0+k)*68 + pxl]   = lrelu(b2f((ushort)v0[k]) * a[c0+k]   + b[c0+k]);
      tf[(c0+8+k)*68 + pxl] = lrelu(b2f((ushort)v1[k]) * a[c0+8+k] + b[c0+8+k]);
    }
  }
  __syncthreads();
  {
    const int c = tid >> 2, part = tid & 3;
    const size_t gb = (size_t)c * N2 + p0 + part * 16;
    float w[16];
    #pragma unroll
    for (int k = 0; k < 16; ++k) w[k] = tf[c*68 + part*16 + k];
    if (doRes){
      #pragma unroll
      for (int k = 0; k < 16; ++k) w[k] += X[gb + k];
      #pragma unroll
      for (int k = 0; k < 16; ++k) tf[c*68 + part*16 + k] = w[k];
    }
    #pragma unroll
    for (int k = 0; k < 16; ++k) X[gb + k] = w[k];
  }
  if (Xb){
    __syncthreads();
    ushort o[16];
    #pragma unroll
    for (int k = 0; k < 16; ++k) o[k] = f2b(tf[(c0+k)*68 + pxl]);
    ushort* xp = &Xb[(size_t)(p0 + pxl) * 64 + c0];
    *(short8*)&xp[0] = *(short8*)&o[0];
    *(short8*)&xp[8] = *(short8*)&o[8];
  }
}

// conv weights [conv][oc][ic][3][3] fp32 -> bf16 [conv][tap][kc][half][oc][8j]
__global__ void wt_k(const float* __restrict__ w, ushort* __restrict__ wt){
  const int i = blockIdx.x * 256 + threadIdx.x;   // 368640
  const int j    = i & 7;
  const int oc   = (i >> 3) & 63;
  const int half = (i >> 9) & 1;
  const int kc   = (i >> 10) & 3;
  const int tap  = (i / 4096) % 9;
  const int cv   = i / 36864;
  const int ic   = kc * 16 + half * 8 + j;
  wt[i] = f2b(w[((size_t)(cv * CH + oc) * CH + ic) * 9 + tap]);
}

// ---------------- direct-global MFMA conv: no LDS staging, no barriers in main loop ----
template<int DIL>
__global__ __launch_bounds__(256, 3) void convd_k(const ushort* __restrict__ in,
                                                  const ushort* __restrict__ wg,
                                                  ushort* __restrict__ out,
                                                  float* __restrict__ part){
  __shared__ __align__(16) unsigned char ldsraw[256 * 136 + 4 * CH * 2 * 4];
  const int tid = threadIdx.x, lane = tid & 63, wid = tid >> 6;
  const int ln = lane & 31, half = lane >> 5;
  const int bx = blockIdx.x % (SL / TX), by = blockIdx.x / (SL / TX);
  const int xg = bx * TX + ln;

  floatx16 acc[2][2];
  #pragma unroll
  for (int mt = 0; mt < 2; ++mt)
    #pragma unroll
    for (int nt = 0; nt < 2; ++nt)
      #pragma unroll
      for (int r = 0; r < 16; ++r) acc[mt][nt][r] = 0.f;

  #pragma unroll
  for (int tap = 0; tap < 9; ++tap){
    const int dy = (tap / 3 - 1) * DIL, dx = (tap % 3 - 1) * DIL;
    const int gx = xg + dx;
    const bool okx = (unsigned)gx < (unsigned)SL;
    const int gy0 = by * TY + 2 * wid + dy;
    const int gy1 = gy0 + 1;
    const bool ok0 = okx && ((unsigned)gy0 < (unsigned)SL);
    const bool ok1 = okx && ((unsigned)gy1 < (unsigned)SL);
    const size_t r0 = ((size_t)(gy0 * SL + gx)) * 64;
    const size_t r1 = ((size_t)(gy1 * SL + gx)) * 64;
    #pragma unroll
    for (int kc = 0; kc < 4; ++kc){
      const ushort* ab = wg + ((size_t)((tap * 4 + kc) * 2 + half)) * 512;
      short8 a0 = *(const short8*)&ab[ln * 8];
      short8 a1 = *(const short8*)&ab[256 + ln * 8];
      const int co = kc * 16 + half * 8;
      short8 b0 = {0,0,0,0,0,0,0,0}, b1 = {0,0,0,0,0,0,0,0};
      if (ok0) b0 = *(const short8*)&in[r0 + co];
      if (ok1) b1 = *(const short8*)&in[r1 + co];
      acc[0][0] = __builtin_amdgcn_mfma_f32_32x32x16_bf16(a0, b0, acc[0][0], 0, 0, 0);
      acc[1][0] = __builtin_amdgcn_mfma_f32_32x32x16_bf16(a1, b0, acc[1][0], 0, 0, 0);
      acc[0][1] = __builtin_amdgcn_mfma_f32_32x32x16_bf16(a0, b1, acc[0][1], 0, 0, 0);
      acc[1][1] = __builtin_amdgcn_mfma_f32_32x32x16_bf16(a1, b1, acc[1][1], 0, 0, 0);
    }
  }

  // epilogue: LDS transpose -> coalesced NHWC stores + fused stats
  ushort* tb = (ushort*)ldsraw;
  float*  sc = (float*)(ldsraw + 256 * 136);
  #pragma unroll
  for (int mt = 0; mt < 2; ++mt)
    #pragma unroll
    for (int nt = 0; nt < 2; ++nt){
      const int pxl = (2*wid + nt) * 32 + ln;
      #pragma unroll
      for (int rq = 0; rq < 4; ++rq){
        const int oc0 = mt*32 + 8*rq + 4*half;
        #pragma unroll
        for (int k = 0; k < 2; ++k){
          const int r = rq*4 + k*2;
          unsigned pk = (unsigned)f2b(acc[mt][nt][r]) | ((unsigned)f2b(acc[mt][nt][r+1]) << 16);
          *(unsigned*)&tb[pxl * 68 + oc0 + k*2] = pk;
        }
      }
    }
  #pragma unroll
  for (int mt = 0; mt < 2; ++mt)
    #pragma unroll
    for (int rq = 0; rq < 4; ++rq)
      #pragma unroll
      for (int t = 0; t < 4; ++t){
        const int r = rq*4 + t;
        float v  = acc[mt][0][r] + acc[mt][1][r];
        float v2 = acc[mt][0][r]*acc[mt][0][r] + acc[mt][1][r]*acc[mt][1][r];
        #pragma unroll
        for (int o = 1; o < 32; o <<= 1){ v += __shfl_xor(v, o, 64); v2 += __shfl_xor(v2, o, 64); }
        if (ln == 0){
          const int oc = mt*32 + 8*rq + 4*half + t;
          sc[(wid*CH + oc)*2] = v; sc[(wid*CH + oc)*2 + 1] = v2;
        }
      }
  __syncthreads();
  {
    const int px = lane >> 1, pt = lane & 1;
    #pragma unroll
    for (int nt = 0; nt < 2; ++nt){
      const int rr = 2*wid + nt;
      const int gy = by*TY + rr;
      const ushort* sp = &tb[(rr*32 + px) * 68 + pt*32];
      ushort* dp = &out[((size_t)(gy * SL) + bx*TX + px) * 64 + pt*32];
      #pragma unroll
      for (int k = 0; k < 8; ++k){
        uint2 v = *(const uint2*)&sp[k*4];
        *(uint2*)&dp[k*4] = v;
      }
    }
  }
  if (tid < CH){
    float sm = 0.f, ss = 0.f;
    #pragma unroll
    for (int w = 0; w < 4; ++w){ sm += sc[(w*CH + tid)*2]; ss += sc[(w*CH + tid)*2 + 1]; }
    part[((size_t)tid * NBLK + blockIdx.x) * 2]     = sm;
    part[((size_t)tid * NBLK + blockIdx.x) * 2 + 1] = ss;
  }
}

static void launch_conv(int dil, const ushort* src, const ushort* wgl,
                        ushort* dst, float* part, hipStream_t s){
  switch (dil){
    case 1:  convd_k<1><<<NBLK, 256, 0, s>>>(src, wgl, dst, part); break;
    case 2:  convd_k<2><<<NBLK, 256, 0, s>>>(src, wgl, dst, part); break;
    default: convd_k<4><<<NBLK, 256, 0, s>>>(src, wgl, dst, part); break;
  }
}

extern "C" void kernel_launch(void* const* d_in, const int* in_sizes, int n_in,
                              void* d_out, int out_size, void* d_ws, size_t ws_size,
                              hipStream_t stream){
  const float* x1d    = (const float*)d_in[0];
  const float* x2     = (const float*)d_in[1];
  const float* W1     = (const float*)d_in[2];
  const float* g1     = (const float*)d_in[3];
  const float* b1     = (const float*)d_in[4];
  const float* W2     = (const float*)d_in[5];
  const float* res_w  = (const float*)d_in[11];
  const float* res_g  = (const float*)d_in[13];
  const float* res_be = (const float*)d_in[14];
  float* X = (float*)d_out;                        // fp32 NCHW residual stream

  unsigned char* wp = (unsigned char*)d_ws;
  ushort* A   = (ushort*)wp; wp += (size_t)N2 * 64 * 2;
  ushort* Bb  = (ushort*)wp; wp += (size_t)N2 * 64 * 2;
  ushort* Xb  = (ushort*)wp; wp += (size_t)N2 * 64 * 2;
  ushort* wt  = (ushort*)wp; wp += (size_t)368640 * 2;
  ushort* w3b = (ushort*)wp; wp += (size_t)8192 * 2;
  float* fw = (float*)wp;
  float* rcP  = fw; fw += 4 * 2 * CH * SL;
  float* rowT = fw; fw += SL * CH;
  float* colT = fw; fw += SL * CH;
  float* s1m  = fw; fw += D1;   float* s1r = fw; fw += D1;
  float* s2m  = fw; fw += 256;  float* s2r = fw; fw += 256;
  float* m1   = fw; fw += 64;   float* rs1 = fw; fw += 64;
  float* aA   = fw; fw += 64;   float* bA  = fw; fw += 64;
  float* aB   = fw; fw += 64;   float* bB  = fw; fw += 64;
  float* w2e  = fw; fw += D2 * CH;
  float* part = fw; fw += CH * NBLK * 2;

  // ---- 1d branch
  stats_k<<<dim3(1, D1), 256, 0, stream>>>(x1d, SL, part);
  stats_final_k<<<(D1 + 255) / 256, 256, 0, stream>>>(part, D1, 1, 1.f / SL, s1m, s1r);
  rowcol_k<<<dim3(2 * CH * SL / 256, 4), 256, 0, stream>>>(x1d, W1, s1r, rcP);
  rowcol_stats_k<<<CH, 256, 0, stream>>>(rcP, m1, rs1);
  rowcolT_k<<<SL * CH / 256, 256, 0, stream>>>(rcP, m1, rs1, g1, b1, rowT, colT);
  pair1n_k<<<N2 * 64 / 4096, 256, 0, stream>>>(rowT, colT, A);

  // ---- 2d branch
  stats_k<<<dim3(16, D2), 256, 0, stream>>>(x2, N2, part);
  stats_final_k<<<1, 256, 0, stream>>>(part, D2, 16, 1.f / N2, s2m, s2r);
  w2eff_k<<<1, 64, 0, stream>>>(W2, s2r, w2e);
  pair2v_k<<<dim3(NBLK, 2), 256, 0, stream>>>(x2, w2e, Bb, part);
  statsaffine_k<<<1, 64, 0, stream>>>(part, NBLK, 1.f / N2,
      (const float*)d_in[6], (const float*)d_in[7], 0, aA, bA);
  norm_nhwc_k<<<N2 * 64 / 4096, 256, 0, stream>>>(Bb, aA, bA);

  // ---- mix (MFMA, in-place over A) + bootstrap X
  w3b_k<<<32, 256, 0, stream>>>((const float*)d_in[8], w3b);
  mixm_k<<<NBLK, 256, 0, stream>>>(A, Bb, w3b, A, part);
  statsaffine_k<<<1, 64, 0, stream>>>(part, NBLK, 1.f / N2,
      (const float*)d_in[9], (const float*)d_in[10], 0, aA, bA);
  norm_res_k<<<N2 / 64, 256, 0, stream>>>(A, aA, bA, X, Xb, 0);

  // ---- conv weights
  wt_k<<<368640 / 256, 256, 0, stream>>>(res_w, wt);

  // ---- 5 residual layers x 2 convs
  const int dil[5] = {1, 2, 4, 2, 1};
  for (int layer = 0; layer < 5; ++layer){
    const int d = dil[layer];
    const int li0 = layer * 2, li1 = li0 + 1;
    launch_conv(d, Xb, wt + (size_t)li0 * 36864, A, part, stream);
    statsaffine_k<<<1, 64, 0, stream>>>(part, NBLK, 1.f / N2, res_g, res_be, li0 * CH, aA, bA);
    norm_nhwc_k<<<N2 * 64 / 4096, 256, 0, stream>>>(A, aA, bA);
    launch_conv(d, A, wt + (size_t)li1 * 36864, Bb, part, stream);
    statsaffine_k<<<1, 64, 0, stream>>>(part, NBLK, 1.f / N2, res_g, res_be, li1 * CH, aB, bB);
    norm_res_k<<<N2 / 64, 256, 0, stream>>>(Bb, aB, bB, X,
        (layer == 4) ? nullptr : Xb, 1);
  }
}